// Round 17
// baseline (881.375 us; speedup 1.0000x reference)
//
#include <hip/hip_runtime.h>
#include <hip/hip_bf16.h>

#define NN 16384
#define DD 300
#define DP 320
#define RR 10
#define BB 1024
#define KK 64
#define CAP 128
#define CAPL 512   // per-block LDS survivor buffer entries per side

typedef __attribute__((ext_vector_type(8))) short s8v;   // 8 bf16 (4 VGPRs)
typedef __attribute__((ext_vector_type(4))) float f4v;   // MFMA accumulator
typedef _Float16 h2 __attribute__((ext_vector_type(2))); // packed fp16 pair

// ---- monotone f16 -> u16 key (order-preserving; packed 2 per dword) -------
__device__ __forceinline__ unsigned mono2(unsigned d) {
    unsigned s = ((d >> 15) & 0x10001u) * 0xFFFFu;
    return d ^ (s | 0x80008000u);
}
__device__ __forceinline__ float key2f16(unsigned k) {
    unsigned short b = (k & 0x8000u) ? (unsigned short)(k ^ 0x8000u)
                                     : (unsigned short)(~k & 0xFFFFu);
    _Float16 hv = __builtin_bit_cast(_Float16, b);
    return (float)hv;
}

__device__ __forceinline__ h2 h2max(h2 a, h2 b) {
    return __builtin_elementwise_max(a, b);
}
__device__ __forceinline__ h2 hmax2s(h2 a, int xb) {
    int x = __shfl_xor(__builtin_bit_cast(int, a), xb);
    return h2max(a, __builtin_bit_cast(h2, x));
}
__device__ __forceinline__ h2 packh2(float a, float b) {
    h2 r; r[0] = (_Float16)a; r[1] = (_Float16)b; return r;
}
__device__ __forceinline__ float max4(f4v v) {
    return fmaxf(fmaxf(v[0], v[1]), fmaxf(v[2], v[3]));
}

// sorted-descending top-10 insert (unsigned keys)
__device__ __forceinline__ void ins10(unsigned (&lst)[10], unsigned v) {
    #pragma unroll
    for (int q = 0; q < 10; ++q) {
        unsigned a  = lst[q];
        unsigned mx = a > v ? a : v;
        v           = a > v ? v : a;
        lst[q] = mx;
    }
}
// float variant
__device__ __forceinline__ void ins10f(float (&lst)[10], float v) {
    #pragma unroll
    for (int q = 0; q < 10; ++q) {
        float a  = lst[q];
        float mx = fmaxf(a, v);
        v        = fminf(a, v);
        lst[q] = mx;
    }
}

// 2D XCD-chunked block mapping (round-10 win: FETCH 661->46 MB)
__device__ __forceinline__ void xcd_map(int bid, int& by, int& bx) {
    const int xcd = bid & 7;
    const int s   = bid >> 3;
    bx = (xcd << 2) | (s & 3);
    by = s >> 2;
}

__device__ __forceinline__ void gload_lds16(const void* g, void* l) {
#if __has_builtin(__builtin_amdgcn_global_load_lds)
    __builtin_amdgcn_global_load_lds(
        (const __attribute__((address_space(1))) void*)g,
        (__attribute__((address_space(3))) void*)l, 16, 0, 0);
#else
    const int lane = threadIdx.x & 63;
    int4 v = *reinterpret_cast<const int4*>(g);
    *reinterpret_cast<int4*>((char*)l + lane * 16) = v;
#endif
}

// Stage A[128][64] + B[128][64] bf16 into `base` (A at +0, B at +16384).
// 4 waves x 8 chunks of 1 KB. Linear LDS dest; XOR-preswizzled source:
// logical layout LDS[row][u] = G[row][u ^ (row&7)].
__device__ __forceinline__ void stage_tile(
        const __hip_bfloat16* __restrict__ Ab, const __hip_bfloat16* __restrict__ Bb,
        int kb, char* base, int w, int lane) {
    const int r8 = lane >> 3;
    const int u  = (lane & 7) ^ r8;
    #pragma unroll
    for (int qq = 0; qq < 8; ++qq) {
        const int chunk = qq * 4 + w;   // 0..31, wave-uniform
        const int cm = chunk & 15;
        const int row = cm * 8 + r8;
        const size_t go = (size_t)row * DP + kb * 64 + u * 8;
        gload_lds16((chunk < 16 ? Ab : Bb) + go,
                    base + (chunk < 16 ? 0 : 16384) + cm * 1024);
    }
}

// ---------------------------------------------------------------------------
// Kernel 1: Householder tower + L2 normalize + bf16 cast (padded to 320).
// ---------------------------------------------------------------------------
__global__ __launch_bounds__(256) void tower_kernel(
        const float* __restrict__ feat, const float* __restrict__ vs,
        __hip_bfloat16* __restrict__ out) {
    __shared__ float vsh[RR * DD];
    const int tid = threadIdx.x;
    for (int i = tid; i < RR * DD; i += 256) vsh[i] = vs[i];
    __syncthreads();

    const int lane = tid & 63;
    const int wave = tid >> 6;
    const int row  = blockIdx.x * 4 + wave;

    float h[5];
    #pragma unroll
    for (int j = 0; j < 5; ++j) {
        int d = lane + 64 * j;
        h[j] = (d < DD) ? feat[(size_t)row * DD + d] : 0.f;
    }
    #pragma unroll
    for (int r = 0; r < RR; ++r) {
        float vl[5];
        float hv = 0.f, vv = 0.f;
        #pragma unroll
        for (int j = 0; j < 5; ++j) {
            int d = lane + 64 * j;
            float v = (d < DD) ? vsh[r * DD + d] : 0.f;
            vl[j] = v;
            hv += h[j] * v;
            vv += v * v;
        }
        #pragma unroll
        for (int o = 32; o; o >>= 1) {
            hv += __shfl_xor(hv, o);
            vv += __shfl_xor(vv, o);
        }
        float coef = hv / vv;
        #pragma unroll
        for (int j = 0; j < 5; ++j) h[j] -= coef * vl[j];
    }
    float nn = 0.f;
    #pragma unroll
    for (int j = 0; j < 5; ++j) nn += h[j] * h[j];
    #pragma unroll
    for (int o = 32; o; o >>= 1) nn += __shfl_xor(nn, o);
    float scale = 1.f / fmaxf(sqrtf(nn), 1e-12f);
    #pragma unroll
    for (int j = 0; j < 5; ++j) {
        int d = lane + 64 * j;
        float val = (d < DD) ? h[j] * scale : 0.f;
        out[(size_t)row * DP + d] = __float2bfloat16(val);
    }
}

// ---- 64x64-per-wave K-loop (m97 geometry): 8 ds_read_b128 : 16 MFMA -------
#define KLOOP64                                                                \
    _Pragma("unroll")                                                          \
    for (int kb = 0; kb < 5; ++kb) {                                           \
        __syncthreads();                                                       \
        stage_tile(Ab, Bb, kb, u_lds, w, lane);                                \
        __syncthreads();                                                       \
        _Pragma("unroll")                                                      \
        for (int ks = 0; ks < 2; ++ks) {                                       \
            s8v af[4], bfv[4];                                                 \
            const int ulog = ks * 4 + (lane >> 4);                             \
            const int up   = ulog ^ (lane & 7);                                \
            _Pragma("unroll")                                                  \
            for (int m = 0; m < 4; ++m) {                                      \
                const int row = wr * 64 + m * 16 + (lane & 15);                \
                af[m] = *reinterpret_cast<const s8v*>(Asub + row * 64 + up * 8); \
            }                                                                  \
            _Pragma("unroll")                                                  \
            for (int n = 0; n < 4; ++n) {                                      \
                const int row = wc * 64 + n * 16 + (lane & 15);                \
                bfv[n] = *reinterpret_cast<const s8v*>(Bsub + row * 64 + up * 8); \
            }                                                                  \
            _Pragma("unroll")                                                  \
            for (int m = 0; m < 4; ++m)                                        \
                _Pragma("unroll")                                              \
                for (int n = 0; n < 4; ++n)                                    \
                    acc[m][n] = __builtin_amdgcn_mfma_f32_16x16x32_bf16(       \
                        af[m], bfv[n], acc[m][n], 0, 0, 0);                    \
        }                                                                      \
    }

// ---------------------------------------------------------------------------
// Kernel 2 (pass A): GEMM + strip-maxes. 256 thr / 4 waves (2x2 grid of
// 64x64 wave-tiles over the 128x128 inner tile). LDS 64 KB -> 2 blocks/CU.
// ---------------------------------------------------------------------------
__global__ __launch_bounds__(256) void passA_kernel(
        const __hip_bfloat16* __restrict__ A, const __hip_bfloat16* __restrict__ Bm,
        unsigned short* __restrict__ rowsmax_g,   // [N][512] u16 keys
        unsigned short* __restrict__ colsmax_g) { // [N][512] u16 keys
    __shared__ __align__(16) char u_lds[32768];
    __shared__ unsigned short rowsm[16][512];   // [strip][row in region]
    __shared__ unsigned short colsm[512][16];   // [col in region][strip]

    const __hip_bfloat16* Asub = (const __hip_bfloat16*)u_lds;
    const __hip_bfloat16* Bsub = (const __hip_bfloat16*)(u_lds + 16384);

    const int tid = threadIdx.x;
    const int lane = tid & 63;
    const int w = tid >> 6;          // 0..3
    const int wr = w >> 1, wc = w & 1;
    int by, bx; xcd_map(blockIdx.x, by, bx);
    const int i0 = by * 512, j0 = bx * 512;

    for (int ti = 0; ti < 4; ++ti) {
        for (int tj = 0; tj < 4; ++tj) {
            f4v acc[4][4];
            #pragma unroll
            for (int m = 0; m < 4; ++m)
                #pragma unroll
                for (int n = 0; n < 4; ++n)
                    acc[m][n] = (f4v){0.f, 0.f, 0.f, 0.f};

            const __hip_bfloat16* Ab = A  + (size_t)(i0 + ti * 128) * DP;
            const __hip_bfloat16* Bb = Bm + (size_t)(j0 + tj * 128) * DP;

            KLOOP64

            // --- row strip-max epilogue: 2 col-pairs (strips of 32 cols) ---
            // C/D layout: col = lane&15, row = (lane>>4)*4 + reg
            #pragma unroll
            for (int p = 0; p < 2; ++p) {
                #pragma unroll
                for (int m = 0; m < 4; ++m) {
                    h2 a01 = h2max(packh2(acc[m][2*p][0],   acc[m][2*p][1]),
                                   packh2(acc[m][2*p+1][0], acc[m][2*p+1][1]));
                    h2 a23 = h2max(packh2(acc[m][2*p][2],   acc[m][2*p][3]),
                                   packh2(acc[m][2*p+1][2], acc[m][2*p+1][3]));
                    a01 = hmax2s(a01, 1); a23 = hmax2s(a23, 1);
                    a01 = hmax2s(a01, 2); a23 = hmax2s(a23, 2);
                    a01 = hmax2s(a01, 4); a23 = hmax2s(a23, 4);
                    a01 = hmax2s(a01, 8); a23 = hmax2s(a23, 8);
                    if ((lane & 15) == m * 4) {
                        const int rl = ti * 128 + wr * 64 + m * 16 + ((lane >> 4) << 2);
                        uint2 u = make_uint2(mono2(__builtin_bit_cast(unsigned, a01)),
                                             mono2(__builtin_bit_cast(unsigned, a23)));
                        *reinterpret_cast<uint2*>(&rowsm[tj * 4 + wc * 2 + p][rl]) = u;
                    }
                }
            }
            // --- col strip-max epilogue: 2 row-pairs (strips of 32 rows) ---
            #pragma unroll
            for (int q = 0; q < 2; ++q) {
                #pragma unroll
                for (int pr = 0; pr < 2; ++pr) {
                    float ra = fmaxf(max4(acc[2*q][2*pr]),   max4(acc[2*q+1][2*pr]));
                    float rb = fmaxf(max4(acc[2*q][2*pr+1]), max4(acc[2*q+1][2*pr+1]));
                    h2 c = packh2(ra, rb);
                    c = hmax2s(c, 16);
                    c = hmax2s(c, 32);
                    if ((lane >> 4) == 0) {
                        const int s = ti * 4 + wr * 2 + q;
                        const int cb = tj * 128 + wc * 64 + pr * 32 + (lane & 15);
                        unsigned k = mono2(__builtin_bit_cast(unsigned, c));
                        colsm[cb][s]      = (unsigned short)(k & 0xFFFFu);
                        colsm[cb + 16][s] = (unsigned short)(k >> 16);
                    }
                }
            }
        }
    }
    __syncthreads();
    // flush strip-maxes (coalesced 32B per row/col)
    for (int r = tid; r < 512; r += 256) {
        unsigned short t16[16];
        #pragma unroll
        for (int s = 0; s < 16; ++s) t16[s] = rowsm[s][r];
        uint4 o0, o1;
        o0.x = t16[0] | ((unsigned)t16[1] << 16);  o0.y = t16[2] | ((unsigned)t16[3] << 16);
        o0.z = t16[4] | ((unsigned)t16[5] << 16);  o0.w = t16[6] | ((unsigned)t16[7] << 16);
        o1.x = t16[8] | ((unsigned)t16[9] << 16);  o1.y = t16[10] | ((unsigned)t16[11] << 16);
        o1.z = t16[12] | ((unsigned)t16[13] << 16); o1.w = t16[14] | ((unsigned)t16[15] << 16);
        uint4* rdst = reinterpret_cast<uint4*>(rowsmax_g + (size_t)(i0 + r) * 512 + bx * 16);
        rdst[0] = o0; rdst[1] = o1;
    }
    for (int r = tid; r < 512; r += 256) {
        uint4 q0 = *reinterpret_cast<uint4*>(&colsm[r][0]);
        uint4 q1 = *reinterpret_cast<uint4*>(&colsm[r][8]);
        uint4* cdst = reinterpret_cast<uint4*>(colsmax_g + (size_t)(j0 + r) * 512 + by * 16);
        cdst[0] = q0; cdst[1] = q1;
    }
}

// ---------------------------------------------------------------------------
// Kernel 3: per row/col, 10th-largest strip-max -> float lower-bound Tlb.
// ---------------------------------------------------------------------------
__global__ __launch_bounds__(256) void thresh_kernel(
        const unsigned short* __restrict__ rowsmax_g,
        const unsigned short* __restrict__ colsmax_g,
        float* __restrict__ Tlb_row, float* __restrict__ Tlb_col,
        unsigned* __restrict__ rowcnt, unsigned* __restrict__ colcnt) {
    const int t = blockIdx.x * 256 + threadIdx.x;
    const bool isRow = t < NN;
    const int idx = isRow ? t : t - NN;
    const unsigned short* src = (isRow ? rowsmax_g : colsmax_g) + (size_t)idx * 512;

    unsigned lst[10];
    #pragma unroll
    for (int q = 0; q < 10; ++q) lst[q] = 0u;

    const uint4* p = reinterpret_cast<const uint4*>(src);
    for (int c = 0; c < 64; ++c) {
        uint4 q = p[c];
        unsigned v0 = q.x & 0xFFFFu, v1 = q.x >> 16;
        unsigned v2 = q.y & 0xFFFFu, v3 = q.y >> 16;
        unsigned v4 = q.z & 0xFFFFu, v5 = q.z >> 16;
        unsigned v6 = q.w & 0xFFFFu, v7 = q.w >> 16;
        unsigned g01 = v0 > v1 ? v0 : v1, g23 = v2 > v3 ? v2 : v3;
        unsigned g45 = v4 > v5 ? v4 : v5, g67 = v6 > v7 ? v6 : v7;
        unsigned ga = g01 > g23 ? g01 : g23, gb = g45 > g67 ? g45 : g67;
        unsigned g = ga > gb ? ga : gb;
        if (g > lst[9]) {
            if (v0 > lst[9]) ins10(lst, v0);
            if (v1 > lst[9]) ins10(lst, v1);
            if (v2 > lst[9]) ins10(lst, v2);
            if (v3 > lst[9]) ins10(lst, v3);
            if (v4 > lst[9]) ins10(lst, v4);
            if (v5 > lst[9]) ins10(lst, v5);
            if (v6 > lst[9]) ins10(lst, v6);
            if (v7 > lst[9]) ins10(lst, v7);
        }
    }
    float f = key2f16(lst[9]);
    float lb = f - fabsf(f) * 0.002f - 1e-6f;   // f16 ulp safety margin
    if (isRow) { Tlb_row[idx] = lb; rowcnt[idx] = 0u; }
    else       { Tlb_col[idx] = lb; colcnt[idx] = 0u; }
}

// ---------------------------------------------------------------------------
// Kernel 4 (pass B): GEMM + threshold filter; survivors via LDS stacks.
// 256 thr / 4 waves, 64x64 wave-tile. LDS ~45 KB -> 3 blocks/CU.
// ---------------------------------------------------------------------------
__global__ __launch_bounds__(256) void passB_kernel(
        const __hip_bfloat16* __restrict__ A, const __hip_bfloat16* __restrict__ Bm,
        const float* __restrict__ Tlb_row, const float* __restrict__ Tlb_col,
        unsigned* __restrict__ rowcnt, unsigned* __restrict__ colcnt,
        float* __restrict__ rowbuf, float* __restrict__ colbuf) {
    __shared__ __align__(16) char u_lds[32768];
    __shared__ float Trow_s[512];
    __shared__ float Tcol_s[512];
    __shared__ unsigned scnt[2];
    __shared__ uint2 sbuf[2][CAPL];

    const __hip_bfloat16* Asub = (const __hip_bfloat16*)u_lds;
    const __hip_bfloat16* Bsub = (const __hip_bfloat16*)(u_lds + 16384);

    const int tid = threadIdx.x;
    const int lane = tid & 63;
    const int w = tid >> 6;          // 0..3
    const int wr = w >> 1, wc = w & 1;
    int by, bx; xcd_map(blockIdx.x, by, bx);
    const int i0 = by * 512, j0 = bx * 512;

    for (int i = tid; i < 512; i += 256) {
        Trow_s[i] = Tlb_row[i0 + i];
        Tcol_s[i] = Tlb_col[j0 + i];
    }
    if (tid < 2) scnt[tid] = 0u;
    __syncthreads();

    for (int ti = 0; ti < 4; ++ti) {
        float trmin = 1e30f;
        #pragma unroll
        for (int m = 0; m < 4; ++m)
            #pragma unroll
            for (int r = 0; r < 4; ++r)
                trmin = fminf(trmin, Trow_s[ti * 128 + wr * 64 + m * 16 + ((lane >> 4) << 2) + r]);

        for (int tj = 0; tj < 4; ++tj) {
            f4v acc[4][4];
            #pragma unroll
            for (int m = 0; m < 4; ++m)
                #pragma unroll
                for (int n = 0; n < 4; ++n)
                    acc[m][n] = (f4v){0.f, 0.f, 0.f, 0.f};

            const __hip_bfloat16* Ab = A  + (size_t)(i0 + ti * 128) * DP;
            const __hip_bfloat16* Bb = Bm + (size_t)(j0 + tj * 128) * DP;

            KLOOP64

            // filter epilogue: push survivors to LDS stacks
            float tc[4];
            #pragma unroll
            for (int n = 0; n < 4; ++n)
                tc[n] = Tcol_s[tj * 128 + wc * 64 + n * 16 + (lane & 15)];
            float tcmin = fminf(fminf(tc[0], tc[1]), fminf(tc[2], tc[3]));
            float vm = -1e30f;
            #pragma unroll
            for (int m = 0; m < 4; ++m)
                #pragma unroll
                for (int n = 0; n < 4; ++n)
                    vm = fmaxf(vm, max4(acc[m][n]));
            if (vm >= fminf(trmin, tcmin)) {
                #pragma unroll
                for (int m = 0; m < 4; ++m) {
                    #pragma unroll
                    for (int r = 0; r < 4; ++r) {
                        const int rl = ti * 128 + wr * 64 + m * 16 + ((lane >> 4) << 2) + r;
                        const float T = Trow_s[rl];
                        #pragma unroll
                        for (int n = 0; n < 4; ++n) {
                            const float v = acc[m][n][r];
                            if (v >= T) {
                                unsigned p = atomicAdd(&scnt[0], 1u);
                                if (p < CAPL) sbuf[0][p] = make_uint2((unsigned)(i0 + rl), __float_as_uint(v));
                                else { unsigned qq = atomicAdd(&rowcnt[i0 + rl], 1u);
                                       if (qq < CAP) rowbuf[(size_t)(i0 + rl) * CAP + qq] = v; }
                            }
                            if (v >= tc[n]) {
                                const int cn = j0 + tj * 128 + wc * 64 + n * 16 + (lane & 15);
                                unsigned p = atomicAdd(&scnt[1], 1u);
                                if (p < CAPL) sbuf[1][p] = make_uint2((unsigned)cn, __float_as_uint(v));
                                else { unsigned qq = atomicAdd(&colcnt[cn], 1u);
                                       if (qq < CAP) colbuf[(size_t)cn * CAP + qq] = v; }
                            }
                        }
                    }
                }
            }
        }
    }

    // parallel flush: independent global atomics, one latency round-trip
    __syncthreads();
    {
        const unsigned nr = scnt[0] < CAPL ? scnt[0] : CAPL;
        const unsigned nc = scnt[1] < CAPL ? scnt[1] : CAPL;
        for (unsigned i = tid; i < nr; i += 256) {
            uint2 e = sbuf[0][i];
            unsigned p = atomicAdd(&rowcnt[e.x], 1u);
            if (p < CAP) rowbuf[(size_t)e.x * CAP + p] = __uint_as_float(e.y);
        }
        for (unsigned i = tid; i < nc; i += 256) {
            uint2 e = sbuf[1][i];
            unsigned p = atomicAdd(&colcnt[e.x], 1u);
            if (p < CAP) colbuf[(size_t)e.x * CAP + p] = __uint_as_float(e.y);
        }
    }
}

// ---------------------------------------------------------------------------
// Kernel 5: exact top-10 of survivors -> rt / rs.
// ---------------------------------------------------------------------------
__global__ __launch_bounds__(256) void final_kernel(
        const unsigned* __restrict__ rowcnt, const unsigned* __restrict__ colcnt,
        const float* __restrict__ rowbuf, const float* __restrict__ colbuf,
        float* __restrict__ rt, float* __restrict__ rs) {
    const int t = blockIdx.x * 256 + threadIdx.x;
    const bool isRow = t < NN;
    const int idx = isRow ? t : t - NN;
    const unsigned cn = (isRow ? rowcnt : colcnt)[idx];
    const int n = (int)(cn < CAP ? cn : CAP);
    const float* buf = (isRow ? rowbuf : colbuf) + (size_t)idx * CAP;

    float lst[10];
    #pragma unroll
    for (int q = 0; q < 10; ++q) lst[q] = -1e30f;
    for (int i = 0; i < n; ++i) {
        float v = buf[i];
        if (v > lst[9]) ins10f(lst, v);
    }
    float s = 0.f;
    #pragma unroll
    for (int q = 0; q < 10; ++q) s += lst[q];
    s *= 0.1f;
    (isRow ? rt : rs)[idx] = s;
}

// ---------------------------------------------------------------------------
// Kernel 6: gathered dots + CSLS logits.
// ---------------------------------------------------------------------------
__global__ __launch_bounds__(256) void logits_kernel(
        const __hip_bfloat16* __restrict__ srcH, const __hip_bfloat16* __restrict__ tgtH,
        const int* __restrict__ sidx, const int* __restrict__ tidx,
        const float* __restrict__ rt, const float* __restrict__ rs,
        float* __restrict__ out) {
    const int b    = blockIdx.x;
    const int lane = threadIdx.x & 63;
    const int w    = threadIdx.x >> 6;

    const int s0 = sidx[b * KK];
    const int t0 = tidx[b * KK];
    float ps[5], pt[5];
    #pragma unroll
    for (int j = 0; j < 5; ++j) {
        int d = lane + 64 * j;
        ps[j] = __bfloat162float(srcH[(size_t)s0 * DP + d]);
        pt[j] = __bfloat162float(tgtH[(size_t)t0 * DP + d]);
    }
    const float rt_s0 = rt[s0];
    const float rs_t0 = rs[t0];

    for (int kk = w; kk < KK; kk += 4) {
        const int it = tidx[b * KK + kk];
        const int is = sidx[b * KK + kk];
        float a = 0.f, c = 0.f;
        #pragma unroll
        for (int j = 0; j < 5; ++j) {
            int d = lane + 64 * j;
            a += ps[j] * __bfloat162float(tgtH[(size_t)it * DP + d]);
            c += pt[j] * __bfloat162float(srcH[(size_t)is * DP + d]);
        }
        #pragma unroll
        for (int o = 32; o; o >>= 1) {
            a += __shfl_xor(a, o);
            c += __shfl_xor(c, o);
        }
        if (lane == 0) {
            out[b * KK + kk]           = 2.f * a - rt_s0 - rs[it];
            out[BB * KK + b * KK + kk] = 2.f * c - rs_t0 - rt[is];
        }
    }
}

// ---------------------------------------------------------------------------
extern "C" void kernel_launch(void* const* d_in, const int* in_sizes, int n_in,
                              void* d_out, int out_size, void* d_ws, size_t ws_size,
                              hipStream_t stream) {
    const float* nf_src = (const float*)d_in[0];
    const float* nf_tgt = (const float*)d_in[1];
    const int*   sidx   = (const int*)d_in[2];
    const int*   tidx   = (const int*)d_in[3];
    const float* svs    = (const float*)d_in[4];
    const float* tvs    = (const float*)d_in[5];

    char* ws = (char*)d_ws;
    const size_t SZ_H  = (size_t)NN * DP * 2;         // bf16 feats
    const size_t SZ_SM = (size_t)NN * 512 * 2;        // strip-maxes
    __hip_bfloat16* srcH = (__hip_bfloat16*)ws;
    __hip_bfloat16* tgtH = (__hip_bfloat16*)(ws + SZ_H);
    unsigned short* rowsmax = (unsigned short*)(ws + 2 * SZ_H);
    unsigned short* colsmax = (unsigned short*)(ws + 2 * SZ_H + SZ_SM);
    // rowbuf/colbuf alias the rowsmax region (consumed by thresh before passB)
    float* rowbuf = (float*)(ws + 2 * SZ_H);
    float* colbuf = (float*)(ws + 2 * SZ_H + (size_t)NN * CAP * 4);
    char* tail = ws + 2 * SZ_H + 2 * SZ_SM;
    float* Tlb_row = (float*)(tail);
    float* Tlb_col = (float*)(tail + 65536);
    unsigned* rowcnt = (unsigned*)(tail + 2 * 65536);
    unsigned* colcnt = (unsigned*)(tail + 3 * 65536);
    float* rt = (float*)(tail + 4 * 65536);
    float* rs = (float*)(tail + 5 * 65536);

    tower_kernel<<<NN / 4, 256, 0, stream>>>(nf_src, svs, srcH);
    tower_kernel<<<NN / 4, 256, 0, stream>>>(nf_tgt, tvs, tgtH);
    passA_kernel<<<1024, 256, 0, stream>>>(srcH, tgtH, rowsmax, colsmax);
    thresh_kernel<<<(2 * NN) / 256, 256, 0, stream>>>(rowsmax, colsmax, Tlb_row, Tlb_col,
                                                      rowcnt, colcnt);
    passB_kernel<<<1024, 256, 0, stream>>>(srcH, tgtH, Tlb_row, Tlb_col,
                                           rowcnt, colcnt, rowbuf, colbuf);
    final_kernel<<<(2 * NN) / 256, 256, 0, stream>>>(rowcnt, colcnt, rowbuf, colbuf, rt, rs);
    logits_kernel<<<BB, 256, 0, stream>>>(srcH, tgtH, sidx, tidx, rt, rs, (float*)d_out);
}

// Round 18
// 703.848 us; speedup vs baseline: 1.2522x; 1.2522x over previous
//
#include <hip/hip_runtime.h>
#include <hip/hip_bf16.h>

#define NN 16384
#define DD 300
#define DP 320
#define RR 10
#define BB 1024
#define KK 64
#define CAP 128
#define CAPL 512   // per-block LDS survivor buffer entries per side

typedef __attribute__((ext_vector_type(8))) short s8v;   // 8 bf16 (4 VGPRs)
typedef __attribute__((ext_vector_type(4))) float f4v;   // MFMA accumulator
typedef _Float16 h2 __attribute__((ext_vector_type(2))); // packed fp16 pair

// ---- monotone f16 -> u16 key (order-preserving; packed 2 per dword) -------
__device__ __forceinline__ unsigned mono2(unsigned d) {
    unsigned s = ((d >> 15) & 0x10001u) * 0xFFFFu;
    return d ^ (s | 0x80008000u);
}
__device__ __forceinline__ float key2f16(unsigned k) {
    unsigned short b = (k & 0x8000u) ? (unsigned short)(k ^ 0x8000u)
                                     : (unsigned short)(~k & 0xFFFFu);
    _Float16 hv = __builtin_bit_cast(_Float16, b);
    return (float)hv;
}

__device__ __forceinline__ h2 h2max(h2 a, h2 b) {
    return __builtin_elementwise_max(a, b);
}
__device__ __forceinline__ h2 hmax2s(h2 a, int xb) {
    int x = __shfl_xor(__builtin_bit_cast(int, a), xb);
    return h2max(a, __builtin_bit_cast(h2, x));
}
__device__ __forceinline__ h2 packh2(float a, float b) {
    h2 r; r[0] = (_Float16)a; r[1] = (_Float16)b; return r;
}

// sorted-descending top-10 insert (unsigned keys)
__device__ __forceinline__ void ins10(unsigned (&lst)[10], unsigned v) {
    #pragma unroll
    for (int q = 0; q < 10; ++q) {
        unsigned a  = lst[q];
        unsigned mx = a > v ? a : v;
        v           = a > v ? v : a;
        lst[q] = mx;
    }
}
// float variant
__device__ __forceinline__ void ins10f(float (&lst)[10], float v) {
    #pragma unroll
    for (int q = 0; q < 10; ++q) {
        float a  = lst[q];
        float mx = fmaxf(a, v);
        v        = fminf(a, v);
        lst[q] = mx;
    }
}

// 2D XCD-chunked block mapping (round-10 win: FETCH 661->46 MB)
__device__ __forceinline__ void xcd_map(int bid, int& by, int& bx) {
    const int xcd = bid & 7;
    const int s   = bid >> 3;
    bx = (xcd << 2) | (s & 3);
    by = s >> 2;
}

__device__ __forceinline__ void gload_lds16(const void* g, void* l) {
#if __has_builtin(__builtin_amdgcn_global_load_lds)
    __builtin_amdgcn_global_load_lds(
        (const __attribute__((address_space(1))) void*)g,
        (__attribute__((address_space(3))) void*)l, 16, 0, 0);
#else
    const int lane = threadIdx.x & 63;
    int4 v = *reinterpret_cast<const int4*>(g);
    *reinterpret_cast<int4*>((char*)l + lane * 16) = v;
#endif
}

// Stage A[128][64] + B[128][64] bf16 into buffer `base` (A at +0, B at +16384).
// 16 waves: wave w stages rows w*8..w*8+7 of both (2 gload_lds per wave).
// Linear LDS dest; XOR-preswizzled source: LDS[row][u] = G[row][u ^ (row&7)].
__device__ __forceinline__ void stage_tile(
        const __hip_bfloat16* __restrict__ Ab, const __hip_bfloat16* __restrict__ Bb,
        int kb, char* base, int w, int lane) {
    const int r8 = lane >> 3;
    const int u  = (lane & 7) ^ r8;
    const int row = w * 8 + r8;
    const size_t go = (size_t)row * DP + kb * 64 + u * 8;
    gload_lds16(Ab + go, base + w * 1024);
    gload_lds16(Bb + go, base + 16384 + w * 1024);
}

// ---------------------------------------------------------------------------
// Kernel 1: Householder tower + L2 normalize + bf16 cast (padded to 320).
// ---------------------------------------------------------------------------
__global__ __launch_bounds__(256) void tower_kernel(
        const float* __restrict__ feat, const float* __restrict__ vs,
        __hip_bfloat16* __restrict__ out) {
    __shared__ float vsh[RR * DD];
    const int tid = threadIdx.x;
    for (int i = tid; i < RR * DD; i += 256) vsh[i] = vs[i];
    __syncthreads();

    const int lane = tid & 63;
    const int wave = tid >> 6;
    const int row  = blockIdx.x * 4 + wave;

    float h[5];
    #pragma unroll
    for (int j = 0; j < 5; ++j) {
        int d = lane + 64 * j;
        h[j] = (d < DD) ? feat[(size_t)row * DD + d] : 0.f;
    }
    #pragma unroll
    for (int r = 0; r < RR; ++r) {
        float vl[5];
        float hv = 0.f, vv = 0.f;
        #pragma unroll
        for (int j = 0; j < 5; ++j) {
            int d = lane + 64 * j;
            float v = (d < DD) ? vsh[r * DD + d] : 0.f;
            vl[j] = v;
            hv += h[j] * v;
            vv += v * v;
        }
        #pragma unroll
        for (int o = 32; o; o >>= 1) {
            hv += __shfl_xor(hv, o);
            vv += __shfl_xor(vv, o);
        }
        float coef = hv / vv;
        #pragma unroll
        for (int j = 0; j < 5; ++j) h[j] -= coef * vl[j];
    }
    float nn = 0.f;
    #pragma unroll
    for (int j = 0; j < 5; ++j) nn += h[j] * h[j];
    #pragma unroll
    for (int o = 32; o; o >>= 1) nn += __shfl_xor(nn, o);
    float scale = 1.f / fmaxf(sqrtf(nn), 1e-12f);
    #pragma unroll
    for (int j = 0; j < 5; ++j) {
        int d = lane + 64 * j;
        float val = (d < DD) ? h[j] * scale : 0.f;
        out[(size_t)row * DP + d] = __float2bfloat16(val);
    }
}

// ---- continuous cross-tile 3-buffer pipeline -------------------------------
// flat step s = t*5+kb; compute from buf[s%3], stage s+2 into buf[(s+2)%3],
// vmcnt(4) keeps 2 stages (4 loads) in flight. 5t % 3 == 2t % 3.
#define COMPUTE_TILE                                                           \
    _Pragma("unroll")                                                          \
    for (int ks = 0; ks < 2; ++ks) {                                           \
        s8v af[2], bfv[2];                                                     \
        const int ulog = ks * 4 + (lane >> 4);                                 \
        const int up   = ulog ^ (lane & 7);                                    \
        _Pragma("unroll")                                                      \
        for (int m = 0; m < 2; ++m) {                                          \
            const int row = wr * 32 + m * 16 + (lane & 15);                    \
            af[m] = *reinterpret_cast<const s8v*>(Asub + row * 64 + up * 8);   \
        }                                                                      \
        _Pragma("unroll")                                                      \
        for (int n = 0; n < 2; ++n) {                                          \
            const int row = wc * 32 + n * 16 + (lane & 15);                    \
            bfv[n] = *reinterpret_cast<const s8v*>(Bsub + row * 64 + up * 8);  \
        }                                                                      \
        _Pragma("unroll")                                                      \
        for (int m = 0; m < 2; ++m)                                            \
            _Pragma("unroll")                                                  \
            for (int n = 0; n < 2; ++n)                                        \
                acc[m][n] = __builtin_amdgcn_mfma_f32_16x16x32_bf16(           \
                    af[m], bfv[n], acc[m][n], 0, 0, 0);                        \
    }

#define KLOOP_FLAT                                                             \
    _Pragma("unroll")                                                          \
    for (int kb = 0; kb < 5; ++kb) {                                           \
        __builtin_amdgcn_s_barrier();                                          \
        if (kb < 3) {                                                          \
            stage_tile(Ab, Bb, kb + 2,                                         \
                       u_lds + ((2 * t + kb + 2) % 3) * 32768, w, lane);       \
        } else if (t < 15) {                                                   \
            stage_tile(An, Bn, kb - 3,                                         \
                       u_lds + ((2 * t + kb + 2) % 3) * 32768, w, lane);       \
        }                                                                      \
        if (t == 15 && kb == 3) { asm volatile("s_waitcnt vmcnt(2)" ::: "memory"); } \
        else if (t == 15 && kb == 4) { asm volatile("s_waitcnt vmcnt(0)" ::: "memory"); } \
        else { asm volatile("s_waitcnt vmcnt(4)" ::: "memory"); }              \
        __builtin_amdgcn_s_barrier();                                          \
        asm volatile("" ::: "memory");                                         \
        {                                                                      \
            const char* curb = u_lds + ((2 * t + kb) % 3) * 32768;             \
            const __hip_bfloat16* Asub = (const __hip_bfloat16*)curb;          \
            const __hip_bfloat16* Bsub = (const __hip_bfloat16*)(curb + 16384);\
            COMPUTE_TILE                                                       \
        }                                                                      \
        asm volatile("" ::: "memory");                                         \
    }

// ---------------------------------------------------------------------------
// Kernel 2 (pass A): GEMM + strip-maxes. 1024 thr / 16 waves, 32x32
// wave-tile, continuous 3-buffer pipeline. LDS 128 KB.
// ---------------------------------------------------------------------------
__global__ __launch_bounds__(1024) void passA_kernel(
        const __hip_bfloat16* __restrict__ A, const __hip_bfloat16* __restrict__ Bm,
        unsigned short* __restrict__ rowsmax_g,   // [N][512] u16 keys
        unsigned short* __restrict__ colsmax_g) { // [N][512] u16 keys
    __shared__ __align__(16) char u_lds[98304];   // 3 x (A|B 128x64)
    __shared__ unsigned short rowsm[16][512];
    __shared__ unsigned short colsm[512][16];

    const int tid = threadIdx.x;
    const int lane = tid & 63;
    const int w = tid >> 6;          // 0..15
    const int wr = w >> 2, wc = w & 3;
    int by, bx; xcd_map(blockIdx.x, by, bx);
    const int i0 = by * 512, j0 = bx * 512;

    // pipeline prologue: stage s=0 (tile0 kb0 -> buf0), s=1 (tile0 kb1 -> buf1)
    {
        const __hip_bfloat16* A0 = A  + (size_t)i0 * DP;
        const __hip_bfloat16* B0 = Bm + (size_t)j0 * DP;
        stage_tile(A0, B0, 0, u_lds, w, lane);
        stage_tile(A0, B0, 1, u_lds + 32768, w, lane);
    }

    for (int t = 0; t < 16; ++t) {
        const int ti = t >> 2, tj = t & 3;
        const __hip_bfloat16* Ab = A  + (size_t)(i0 + ti * 128) * DP;
        const __hip_bfloat16* Bb = Bm + (size_t)(j0 + tj * 128) * DP;
        const int tn = (t + 1) & 15;
        const __hip_bfloat16* An = A  + (size_t)(i0 + (tn >> 2) * 128) * DP;
        const __hip_bfloat16* Bn = Bm + (size_t)(j0 + (tn & 3) * 128) * DP;

        f4v acc[2][2];
        #pragma unroll
        for (int m = 0; m < 2; ++m)
            #pragma unroll
            for (int n = 0; n < 2; ++n)
                acc[m][n] = (f4v){0.f, 0.f, 0.f, 0.f};

        KLOOP_FLAT

        // --- row strip-max epilogue (strip = this wave's 32 cols) ---
        // C/D layout: col = lane&15, row = (lane>>4)*4 + reg
        #pragma unroll
        for (int m = 0; m < 2; ++m) {
            h2 a01 = h2max(packh2(acc[m][0][0], acc[m][0][1]),
                           packh2(acc[m][1][0], acc[m][1][1]));
            h2 a23 = h2max(packh2(acc[m][0][2], acc[m][0][3]),
                           packh2(acc[m][1][2], acc[m][1][3]));
            a01 = hmax2s(a01, 1); a23 = hmax2s(a23, 1);
            a01 = hmax2s(a01, 2); a23 = hmax2s(a23, 2);
            a01 = hmax2s(a01, 4); a23 = hmax2s(a23, 4);
            a01 = hmax2s(a01, 8); a23 = hmax2s(a23, 8);
            if ((lane & 15) == m * 8) {
                const int rl = ti * 128 + wr * 32 + m * 16 + ((lane >> 4) << 2);
                uint2 u = make_uint2(mono2(__builtin_bit_cast(unsigned, a01)),
                                     mono2(__builtin_bit_cast(unsigned, a23)));
                *reinterpret_cast<uint2*>(&rowsm[tj * 4 + wc][rl]) = u;
            }
        }
        // --- col strip-max epilogue (strip = wave's 32 rows) ---
        {
            float rm0 = -1e30f, rm1 = -1e30f;
            #pragma unroll
            for (int m = 0; m < 2; ++m) {
                rm0 = fmaxf(rm0, fmaxf(fmaxf(acc[m][0][0], acc[m][0][1]),
                                       fmaxf(acc[m][0][2], acc[m][0][3])));
                rm1 = fmaxf(rm1, fmaxf(fmaxf(acc[m][1][0], acc[m][1][1]),
                                       fmaxf(acc[m][1][2], acc[m][1][3])));
            }
            h2 c = packh2(rm0, rm1);
            c = hmax2s(c, 16);
            c = hmax2s(c, 32);
            if ((lane >> 4) == 0) {
                const int s = ti * 4 + wr;
                const int cb = tj * 128 + wc * 32 + (lane & 15);
                unsigned k = mono2(__builtin_bit_cast(unsigned, c));
                colsm[cb][s]      = (unsigned short)(k & 0xFFFFu);
                colsm[cb + 16][s] = (unsigned short)(k >> 16);
            }
        }
    }
    __syncthreads();
    // flush strip-maxes: tid<512 rows, tid>=512 cols (parallel)
    if (tid < 512) {
        const int r = tid;
        unsigned short t16[16];
        #pragma unroll
        for (int s = 0; s < 16; ++s) t16[s] = rowsm[s][r];
        uint4 o0, o1;
        o0.x = t16[0] | ((unsigned)t16[1] << 16);  o0.y = t16[2] | ((unsigned)t16[3] << 16);
        o0.z = t16[4] | ((unsigned)t16[5] << 16);  o0.w = t16[6] | ((unsigned)t16[7] << 16);
        o1.x = t16[8] | ((unsigned)t16[9] << 16);  o1.y = t16[10] | ((unsigned)t16[11] << 16);
        o1.z = t16[12] | ((unsigned)t16[13] << 16); o1.w = t16[14] | ((unsigned)t16[15] << 16);
        uint4* rdst = reinterpret_cast<uint4*>(rowsmax_g + (size_t)(i0 + r) * 512 + bx * 16);
        rdst[0] = o0; rdst[1] = o1;
    } else {
        const int r = tid - 512;
        uint4 q0 = *reinterpret_cast<uint4*>(&colsm[r][0]);
        uint4 q1 = *reinterpret_cast<uint4*>(&colsm[r][8]);
        uint4* cdst = reinterpret_cast<uint4*>(colsmax_g + (size_t)(j0 + r) * 512 + by * 16);
        cdst[0] = q0; cdst[1] = q1;
    }
}

// ---------------------------------------------------------------------------
// Kernel 3: per row/col, 10th-largest strip-max -> float lower-bound Tlb.
// ---------------------------------------------------------------------------
__global__ __launch_bounds__(256) void thresh_kernel(
        const unsigned short* __restrict__ rowsmax_g,
        const unsigned short* __restrict__ colsmax_g,
        float* __restrict__ Tlb_row, float* __restrict__ Tlb_col,
        unsigned* __restrict__ rowcnt, unsigned* __restrict__ colcnt) {
    const int t = blockIdx.x * 256 + threadIdx.x;
    const bool isRow = t < NN;
    const int idx = isRow ? t : t - NN;
    const unsigned short* src = (isRow ? rowsmax_g : colsmax_g) + (size_t)idx * 512;

    unsigned lst[10];
    #pragma unroll
    for (int q = 0; q < 10; ++q) lst[q] = 0u;

    const uint4* p = reinterpret_cast<const uint4*>(src);
    for (int c = 0; c < 64; ++c) {
        uint4 q = p[c];
        unsigned v0 = q.x & 0xFFFFu, v1 = q.x >> 16;
        unsigned v2 = q.y & 0xFFFFu, v3 = q.y >> 16;
        unsigned v4 = q.z & 0xFFFFu, v5 = q.z >> 16;
        unsigned v6 = q.w & 0xFFFFu, v7 = q.w >> 16;
        unsigned g01 = v0 > v1 ? v0 : v1, g23 = v2 > v3 ? v2 : v3;
        unsigned g45 = v4 > v5 ? v4 : v5, g67 = v6 > v7 ? v6 : v7;
        unsigned ga = g01 > g23 ? g01 : g23, gb = g45 > g67 ? g45 : g67;
        unsigned g = ga > gb ? ga : gb;
        if (g > lst[9]) {
            if (v0 > lst[9]) ins10(lst, v0);
            if (v1 > lst[9]) ins10(lst, v1);
            if (v2 > lst[9]) ins10(lst, v2);
            if (v3 > lst[9]) ins10(lst, v3);
            if (v4 > lst[9]) ins10(lst, v4);
            if (v5 > lst[9]) ins10(lst, v5);
            if (v6 > lst[9]) ins10(lst, v6);
            if (v7 > lst[9]) ins10(lst, v7);
        }
    }
    float f = key2f16(lst[9]);
    float lb = f - fabsf(f) * 0.002f - 1e-6f;   // f16 ulp safety margin
    if (isRow) { Tlb_row[idx] = lb; rowcnt[idx] = 0u; }
    else       { Tlb_col[idx] = lb; colcnt[idx] = 0u; }
}

// ---------------------------------------------------------------------------
// Kernel 4 (pass B): GEMM + threshold filter; survivors via LDS stacks.
// Continuous 3-buffer pipeline; LDS ~110 KB.
// ---------------------------------------------------------------------------
__global__ __launch_bounds__(1024) void passB_kernel(
        const __hip_bfloat16* __restrict__ A, const __hip_bfloat16* __restrict__ Bm,
        const float* __restrict__ Tlb_row, const float* __restrict__ Tlb_col,
        unsigned* __restrict__ rowcnt, unsigned* __restrict__ colcnt,
        float* __restrict__ rowbuf, float* __restrict__ colbuf) {
    __shared__ __align__(16) char u_lds[98304];
    __shared__ float Trow_s[512];
    __shared__ float Tcol_s[512];
    __shared__ unsigned scnt[2];
    __shared__ uint2 sbuf[2][CAPL];

    const int tid = threadIdx.x;
    const int lane = tid & 63;
    const int w = tid >> 6;          // 0..15
    const int wr = w >> 2, wc = w & 3;
    int by, bx; xcd_map(blockIdx.x, by, bx);
    const int i0 = by * 512, j0 = bx * 512;

    if (tid < 512) Trow_s[tid] = Tlb_row[i0 + tid];
    else           Tcol_s[tid - 512] = Tlb_col[j0 + tid - 512];
    if (tid < 2) scnt[tid] = 0u;
    __syncthreads();

    // pipeline prologue
    {
        const __hip_bfloat16* A0 = A  + (size_t)i0 * DP;
        const __hip_bfloat16* B0 = Bm + (size_t)j0 * DP;
        stage_tile(A0, B0, 0, u_lds, w, lane);
        stage_tile(A0, B0, 1, u_lds + 32768, w, lane);
    }

    for (int t = 0; t < 16; ++t) {
        const int ti = t >> 2, tj = t & 3;
        const __hip_bfloat16* Ab = A  + (size_t)(i0 + ti * 128) * DP;
        const __hip_bfloat16* Bb = Bm + (size_t)(j0 + tj * 128) * DP;
        const int tn = (t + 1) & 15;
        const __hip_bfloat16* An = A  + (size_t)(i0 + (tn >> 2) * 128) * DP;
        const __hip_bfloat16* Bn = Bm + (size_t)(j0 + (tn & 3) * 128) * DP;

        float trmin = 1e30f;
        #pragma unroll
        for (int m = 0; m < 2; ++m)
            #pragma unroll
            for (int r = 0; r < 4; ++r)
                trmin = fminf(trmin, Trow_s[ti * 128 + wr * 32 + m * 16 + ((lane >> 4) << 2) + r]);

        f4v acc[2][2];
        #pragma unroll
        for (int m = 0; m < 2; ++m)
            #pragma unroll
            for (int n = 0; n < 2; ++n)
                acc[m][n] = (f4v){0.f, 0.f, 0.f, 0.f};

        KLOOP_FLAT

        // filter epilogue: push survivors to LDS stacks
        const int c0i = tj * 128 + wc * 32 + (lane & 15);
        const int c1i = c0i + 16;
        const float tc0 = Tcol_s[c0i], tc1 = Tcol_s[c1i];
        float vm = -1e30f;
        #pragma unroll
        for (int m = 0; m < 2; ++m) {
            float a = fmaxf(fmaxf(acc[m][0][0], acc[m][0][1]),
                            fmaxf(acc[m][0][2], acc[m][0][3]));
            float b = fmaxf(fmaxf(acc[m][1][0], acc[m][1][1]),
                            fmaxf(acc[m][1][2], acc[m][1][3]));
            vm = fmaxf(vm, fmaxf(a, b));
        }
        if (vm >= fminf(trmin, fminf(tc0, tc1))) {
            #pragma unroll
            for (int m = 0; m < 2; ++m) {
                #pragma unroll
                for (int r = 0; r < 4; ++r) {
                    const int rl = ti * 128 + wr * 32 + m * 16 + ((lane >> 4) << 2) + r;
                    const float T = Trow_s[rl];
                    const float v0 = acc[m][0][r], v1 = acc[m][1][r];
                    if (v0 >= T) {
                        unsigned p = atomicAdd(&scnt[0], 1u);
                        if (p < CAPL) sbuf[0][p] = make_uint2((unsigned)(i0 + rl), __float_as_uint(v0));
                        else { unsigned q = atomicAdd(&rowcnt[i0 + rl], 1u);
                               if (q < CAP) rowbuf[(size_t)(i0 + rl) * CAP + q] = v0; }
                    }
                    if (v1 >= T) {
                        unsigned p = atomicAdd(&scnt[0], 1u);
                        if (p < CAPL) sbuf[0][p] = make_uint2((unsigned)(i0 + rl), __float_as_uint(v1));
                        else { unsigned q = atomicAdd(&rowcnt[i0 + rl], 1u);
                               if (q < CAP) rowbuf[(size_t)(i0 + rl) * CAP + q] = v1; }
                    }
                    if (v0 >= tc0) {
                        unsigned p = atomicAdd(&scnt[1], 1u);
                        if (p < CAPL) sbuf[1][p] = make_uint2((unsigned)(j0 + c0i), __float_as_uint(v0));
                        else { unsigned q = atomicAdd(&colcnt[j0 + c0i], 1u);
                               if (q < CAP) colbuf[(size_t)(j0 + c0i) * CAP + q] = v0; }
                    }
                    if (v1 >= tc1) {
                        unsigned p = atomicAdd(&scnt[1], 1u);
                        if (p < CAPL) sbuf[1][p] = make_uint2((unsigned)(j0 + c1i), __float_as_uint(v1));
                        else { unsigned q = atomicAdd(&colcnt[j0 + c1i], 1u);
                               if (q < CAP) colbuf[(size_t)(j0 + c1i) * CAP + q] = v1; }
                    }
                }
            }
        }
    }

    // parallel flush: independent global atomics, one latency round-trip
    __syncthreads();
    {
        const unsigned nr = scnt[0] < CAPL ? scnt[0] : CAPL;
        const unsigned nc = scnt[1] < CAPL ? scnt[1] : CAPL;
        for (unsigned i = tid; i < nr; i += 1024) {
            uint2 e = sbuf[0][i];
            unsigned p = atomicAdd(&rowcnt[e.x], 1u);
            if (p < CAP) rowbuf[(size_t)e.x * CAP + p] = __uint_as_float(e.y);
        }
        for (unsigned i = tid; i < nc; i += 1024) {
            uint2 e = sbuf[1][i];
            unsigned p = atomicAdd(&colcnt[e.x], 1u);
            if (p < CAP) colbuf[(size_t)e.x * CAP + p] = __uint_as_float(e.y);
        }
    }
}

// ---------------------------------------------------------------------------
// Kernel 5: exact top-10 of survivors -> rt / rs.
// ---------------------------------------------------------------------------
__global__ __launch_bounds__(256) void final_kernel(
        const unsigned* __restrict__ rowcnt, const unsigned* __restrict__ colcnt,
        const float* __restrict__ rowbuf, const float* __restrict__ colbuf,
        float* __restrict__ rt, float* __restrict__ rs) {
    const int t = blockIdx.x * 256 + threadIdx.x;
    const bool isRow = t < NN;
    const int idx = isRow ? t : t - NN;
    const unsigned cn = (isRow ? rowcnt : colcnt)[idx];
    const int n = (int)(cn < CAP ? cn : CAP);
    const float* buf = (isRow ? rowbuf : colbuf) + (size_t)idx * CAP;

    float lst[10];
    #pragma unroll
    for (int q = 0; q < 10; ++q) lst[q] = -1e30f;
    for (int i = 0; i < n; ++i) {
        float v = buf[i];
        if (v > lst[9]) ins10f(lst, v);
    }
    float s = 0.f;
    #pragma unroll
    for (int q = 0; q < 10; ++q) s += lst[q];
    s *= 0.1f;
    (isRow ? rt : rs)[idx] = s;
}

// ---------------------------------------------------------------------------
// Kernel 6: gathered dots + CSLS logits.
// ---------------------------------------------------------------------------
__global__ __launch_bounds__(256) void logits_kernel(
        const __hip_bfloat16* __restrict__ srcH, const __hip_bfloat16* __restrict__ tgtH,
        const int* __restrict__ sidx, const int* __restrict__ tidx,
        const float* __restrict__ rt, const float* __restrict__ rs,
        float* __restrict__ out) {
    const int b    = blockIdx.x;
    const int lane = threadIdx.x & 63;
    const int w    = threadIdx.x >> 6;

    const int s0 = sidx[b * KK];
    const int t0 = tidx[b * KK];
    float ps[5], pt[5];
    #pragma unroll
    for (int j = 0; j < 5; ++j) {
        int d = lane + 64 * j;
        ps[j] = __bfloat162float(srcH[(size_t)s0 * DP + d]);
        pt[j] = __bfloat162float(tgtH[(size_t)t0 * DP + d]);
    }
    const float rt_s0 = rt[s0];
    const float rs_t0 = rs[t0];

    for (int kk = w; kk < KK; kk += 4) {
        const int it = tidx[b * KK + kk];
        const int is = sidx[b * KK + kk];
        float a = 0.f, c = 0.f;
        #pragma unroll
        for (int j = 0; j < 5; ++j) {
            int d = lane + 64 * j;
            a += ps[j] * __bfloat162float(tgtH[(size_t)it * DP + d]);
            c += pt[j] * __bfloat162float(srcH[(size_t)is * DP + d]);
        }
        #pragma unroll
        for (int o = 32; o; o >>= 1) {
            a += __shfl_xor(a, o);
            c += __shfl_xor(c, o);
        }
        if (lane == 0) {
            out[b * KK + kk]           = 2.f * a - rt_s0 - rs[it];
            out[BB * KK + b * KK + kk] = 2.f * c - rs_t0 - rt[is];
        }
    }
}

// ---------------------------------------------------------------------------
extern "C" void kernel_launch(void* const* d_in, const int* in_sizes, int n_in,
                              void* d_out, int out_size, void* d_ws, size_t ws_size,
                              hipStream_t stream) {
    const float* nf_src = (const float*)d_in[0];
    const float* nf_tgt = (const float*)d_in[1];
    const int*   sidx   = (const int*)d_in[2];
    const int*   tidx   = (const int*)d_in[3];
    const float* svs    = (const float*)d_in[4];
    const float* tvs    = (const float*)d_in[5];

    char* ws = (char*)d_ws;
    const size_t SZ_H  = (size_t)NN * DP * 2;         // bf16 feats
    const size_t SZ_SM = (size_t)NN * 512 * 2;        // strip-maxes
    __hip_bfloat16* srcH = (__hip_bfloat16*)ws;
    __hip_bfloat16* tgtH = (__hip_bfloat16*)(ws + SZ_H);
    unsigned short* rowsmax = (unsigned short*)(ws + 2 * SZ_H);
    unsigned short* colsmax = (unsigned short*)(ws + 2 * SZ_H + SZ_SM);
    // rowbuf/colbuf alias the rowsmax region (consumed by thresh before passB)
    float* rowbuf = (float*)(ws + 2 * SZ_H);
    float* colbuf = (float*)(ws + 2 * SZ_H + (size_t)NN * CAP * 4);
    char* tail = ws + 2 * SZ_H + 2 * SZ_SM;
    float* Tlb_row = (float*)(tail);
    float* Tlb_col = (float*)(tail + 65536);
    unsigned* rowcnt = (unsigned*)(tail + 2 * 65536);
    unsigned* colcnt = (unsigned*)(tail + 3 * 65536);
    float* rt = (float*)(tail + 4 * 65536);
    float* rs = (float*)(tail + 5 * 65536);

    tower_kernel<<<NN / 4, 256, 0, stream>>>(nf_src, svs, srcH);
    tower_kernel<<<NN / 4, 256, 0, stream>>>(nf_tgt, tvs, tgtH);
    passA_kernel<<<1024, 1024, 0, stream>>>(srcH, tgtH, rowsmax, colsmax);
    thresh_kernel<<<(2 * NN) / 256, 256, 0, stream>>>(rowsmax, colsmax, Tlb_row, Tlb_col,
                                                      rowcnt, colcnt);
    passB_kernel<<<1024, 1024, 0, stream>>>(srcH, tgtH, Tlb_row, Tlb_col,
                                            rowcnt, colcnt, rowbuf, colbuf);
    final_kernel<<<(2 * NN) / 256, 256, 0, stream>>>(rowcnt, colcnt, rowbuf, colbuf, rt, rs);
    logits_kernel<<<BB, 256, 0, stream>>>(srcH, tgtH, sidx, tidx, rt, rs, (float*)d_out);
}

// Round 19
// 703.120 us; speedup vs baseline: 1.2535x; 1.0010x over previous
//
#include <hip/hip_runtime.h>
#include <hip/hip_bf16.h>

#define NN 16384
#define DD 300
#define DP 320
#define RR 10
#define BB 1024
#define KK 64
#define CAP 128
#define CAPL 512   // per-block LDS survivor buffer entries per side

typedef __attribute__((ext_vector_type(8))) short s8v;   // 8 bf16 (4 VGPRs)
typedef __attribute__((ext_vector_type(4))) float f4v;   // MFMA accumulator
typedef _Float16 h2 __attribute__((ext_vector_type(2))); // packed fp16 pair

// ---- monotone f16 -> u16 key (order-preserving; packed 2 per dword) -------
__device__ __forceinline__ unsigned mono2(unsigned d) {
    unsigned s = ((d >> 15) & 0x10001u) * 0xFFFFu;
    return d ^ (s | 0x80008000u);
}
__device__ __forceinline__ float key2f16(unsigned k) {
    unsigned short b = (k & 0x8000u) ? (unsigned short)(k ^ 0x8000u)
                                     : (unsigned short)(~k & 0xFFFFu);
    _Float16 hv = __builtin_bit_cast(_Float16, b);
    return (float)hv;
}

__device__ __forceinline__ h2 h2max(h2 a, h2 b) {
    return __builtin_elementwise_max(a, b);
}
__device__ __forceinline__ h2 hmax2s(h2 a, int xb) {
    int x = __shfl_xor(__builtin_bit_cast(int, a), xb);
    return h2max(a, __builtin_bit_cast(h2, x));
}
__device__ __forceinline__ h2 packh2(float a, float b) {
    h2 r; r[0] = (_Float16)a; r[1] = (_Float16)b; return r;
}
__device__ __forceinline__ float max4(f4v v) {
    return fmaxf(fmaxf(v[0], v[1]), fmaxf(v[2], v[3]));
}

// sorted-descending top-10 insert (unsigned keys)
__device__ __forceinline__ void ins10(unsigned (&lst)[10], unsigned v) {
    #pragma unroll
    for (int q = 0; q < 10; ++q) {
        unsigned a  = lst[q];
        unsigned mx = a > v ? a : v;
        v           = a > v ? v : a;
        lst[q] = mx;
    }
}
// float variant
__device__ __forceinline__ void ins10f(float (&lst)[10], float v) {
    #pragma unroll
    for (int q = 0; q < 10; ++q) {
        float a  = lst[q];
        float mx = fmaxf(a, v);
        v        = fminf(a, v);
        lst[q] = mx;
    }
}

// 2D XCD-chunked block mapping (round-10 win: FETCH 661->46 MB)
__device__ __forceinline__ void xcd_map(int bid, int& by, int& bx) {
    const int xcd = bid & 7;
    const int s   = bid >> 3;
    bx = (xcd << 2) | (s & 3);
    by = s >> 2;
}

__device__ __forceinline__ void gload_lds16(const void* g, void* l) {
#if __has_builtin(__builtin_amdgcn_global_load_lds)
    __builtin_amdgcn_global_load_lds(
        (const __attribute__((address_space(1))) void*)g,
        (__attribute__((address_space(3))) void*)l, 16, 0, 0);
#else
    const int lane = threadIdx.x & 63;
    int4 v = *reinterpret_cast<const int4*>(g);
    *reinterpret_cast<int4*>((char*)l + lane * 16) = v;
#endif
}

// Stage A[128][64] + B[128][64] bf16 into buffer `base` (A +0, B +16384).
// 8 waves x 2 chunks each (4 gload_lds per wave). Linear LDS dest;
// XOR-preswizzled source: LDS[row][u] = G[row][u ^ (row&7)].
__device__ __forceinline__ void stage_tile(
        const __hip_bfloat16* __restrict__ Ab, const __hip_bfloat16* __restrict__ Bb,
        int kb, char* base, int w, int lane) {
    const int r8 = lane >> 3;
    const int u  = (lane & 7) ^ r8;
    #pragma unroll
    for (int c = 0; c < 2; ++c) {
        const int chunk = w * 2 + c;          // 0..15
        const int row = chunk * 8 + r8;
        const size_t go = (size_t)row * DP + kb * 64 + u * 8;
        gload_lds16(Ab + go, base + chunk * 1024);
        gload_lds16(Bb + go, base + 16384 + chunk * 1024);
    }
}

// ---------------------------------------------------------------------------
// Kernel 1: Householder tower + L2 normalize + bf16 cast (padded to 320).
// ---------------------------------------------------------------------------
__global__ __launch_bounds__(256) void tower_kernel(
        const float* __restrict__ feat, const float* __restrict__ vs,
        __hip_bfloat16* __restrict__ out) {
    __shared__ float vsh[RR * DD];
    const int tid = threadIdx.x;
    for (int i = tid; i < RR * DD; i += 256) vsh[i] = vs[i];
    __syncthreads();

    const int lane = tid & 63;
    const int wave = tid >> 6;
    const int row  = blockIdx.x * 4 + wave;

    float h[5];
    #pragma unroll
    for (int j = 0; j < 5; ++j) {
        int d = lane + 64 * j;
        h[j] = (d < DD) ? feat[(size_t)row * DD + d] : 0.f;
    }
    #pragma unroll
    for (int r = 0; r < RR; ++r) {
        float vl[5];
        float hv = 0.f, vv = 0.f;
        #pragma unroll
        for (int j = 0; j < 5; ++j) {
            int d = lane + 64 * j;
            float v = (d < DD) ? vsh[r * DD + d] : 0.f;
            vl[j] = v;
            hv += h[j] * v;
            vv += v * v;
        }
        #pragma unroll
        for (int o = 32; o; o >>= 1) {
            hv += __shfl_xor(hv, o);
            vv += __shfl_xor(vv, o);
        }
        float coef = hv / vv;
        #pragma unroll
        for (int j = 0; j < 5; ++j) h[j] -= coef * vl[j];
    }
    float nn = 0.f;
    #pragma unroll
    for (int j = 0; j < 5; ++j) nn += h[j] * h[j];
    #pragma unroll
    for (int o = 32; o; o >>= 1) nn += __shfl_xor(nn, o);
    float scale = 1.f / fmaxf(sqrtf(nn), 1e-12f);
    #pragma unroll
    for (int j = 0; j < 5; ++j) {
        int d = lane + 64 * j;
        float val = (d < DD) ? h[j] * scale : 0.f;
        out[(size_t)row * DP + d] = __float2bfloat16(val);
    }
}

// ---- 32x64-per-wave K-loop (8 waves, 4x2 grid; 12 ds_read : 16 MFMA) ------
#define COMPUTE_TILE                                                           \
    _Pragma("unroll")                                                          \
    for (int ks = 0; ks < 2; ++ks) {                                           \
        s8v af[2], bfv[4];                                                     \
        const int ulog = ks * 4 + (lane >> 4);                                 \
        const int up   = ulog ^ (lane & 7);                                    \
        _Pragma("unroll")                                                      \
        for (int m = 0; m < 2; ++m) {                                          \
            const int row = wr * 32 + m * 16 + (lane & 15);                    \
            af[m] = *reinterpret_cast<const s8v*>(Asub + row * 64 + up * 8);   \
        }                                                                      \
        _Pragma("unroll")                                                      \
        for (int n = 0; n < 4; ++n) {                                          \
            const int row = wc * 64 + n * 16 + (lane & 15);                    \
            bfv[n] = *reinterpret_cast<const s8v*>(Bsub + row * 64 + up * 8);  \
        }                                                                      \
        _Pragma("unroll")                                                      \
        for (int m = 0; m < 2; ++m)                                            \
            _Pragma("unroll")                                                  \
            for (int n = 0; n < 4; ++n)                                        \
                acc[m][n] = __builtin_amdgcn_mfma_f32_16x16x32_bf16(           \
                    af[m], bfv[n], acc[m][n], 0, 0, 0);                        \
    }

// 2-buffer pipelined K-loop (round-16 proven shape; 4 loads per stage)
#define KLOOP                                                                  \
    stage_tile(Ab, Bb, 0, u_lds, w, lane);                                     \
    _Pragma("unroll")                                                          \
    for (int kb = 0; kb < 5; ++kb) {                                           \
        if (kb < 4)                                                            \
            stage_tile(Ab, Bb, kb + 1, u_lds + ((kb + 1) & 1) * 32768, w, lane); \
        if (kb < 4) { asm volatile("s_waitcnt vmcnt(4)" ::: "memory"); }       \
        else        { asm volatile("s_waitcnt vmcnt(0)" ::: "memory"); }       \
        __builtin_amdgcn_s_barrier();                                          \
        asm volatile("" ::: "memory");                                         \
        {                                                                      \
            const char* curb = u_lds + (kb & 1) * 32768;                       \
            const __hip_bfloat16* Asub = (const __hip_bfloat16*)curb;          \
            const __hip_bfloat16* Bsub = (const __hip_bfloat16*)(curb + 16384);\
            COMPUTE_TILE                                                       \
        }                                                                      \
        asm volatile("" ::: "memory");                                         \
        __builtin_amdgcn_s_barrier();                                          \
    }

// ---------------------------------------------------------------------------
// Kernel 2 (pass A): GEMM + strip-maxes written directly to global in
// block-contiguous [bx][N][16] layout. 512 thr / 8 waves; LDS 64 KB ->
// 2 blocks/CU (regs ~100 incl AGPR -> 16 waves fit the 2048 pool).
// ---------------------------------------------------------------------------
__global__ __launch_bounds__(512) void passA_kernel(
        const __hip_bfloat16* __restrict__ A, const __hip_bfloat16* __restrict__ Bm,
        unsigned short* __restrict__ rowT,   // [32 bx][N][16] u16 keys
        unsigned short* __restrict__ colT) { // [32 by][N][16] u16 keys
    __shared__ __align__(16) char u_lds[65536];   // 2 x (A|B 128x64)

    const int tid = threadIdx.x;
    const int lane = tid & 63;
    const int w = tid >> 6;          // 0..7
    const int wr = w >> 1, wc = w & 1;
    int by, bx; xcd_map(blockIdx.x, by, bx);
    const int i0 = by * 512, j0 = bx * 512;

    for (int ti = 0; ti < 4; ++ti) {
        for (int tj = 0; tj < 4; ++tj) {
            f4v acc[2][4];
            #pragma unroll
            for (int m = 0; m < 2; ++m)
                #pragma unroll
                for (int n = 0; n < 4; ++n)
                    acc[m][n] = (f4v){0.f, 0.f, 0.f, 0.f};

            const __hip_bfloat16* Ab = A  + (size_t)(i0 + ti * 128) * DP;
            const __hip_bfloat16* Bb = Bm + (size_t)(j0 + tj * 128) * DP;

            KLOOP

            // --- row strip-maxes: 2 strips of 32 cols per wave ---
            // C/D layout: col = lane&15, row = (lane>>4)*4 + reg
            #pragma unroll
            for (int p = 0; p < 2; ++p) {
                #pragma unroll
                for (int m = 0; m < 2; ++m) {
                    h2 a01 = h2max(packh2(acc[m][2*p][0],   acc[m][2*p][1]),
                                   packh2(acc[m][2*p+1][0], acc[m][2*p+1][1]));
                    h2 a23 = h2max(packh2(acc[m][2*p][2],   acc[m][2*p][3]),
                                   packh2(acc[m][2*p+1][2], acc[m][2*p+1][3]));
                    a01 = hmax2s(a01, 1); a23 = hmax2s(a23, 1);
                    a01 = hmax2s(a01, 2); a23 = hmax2s(a23, 2);
                    a01 = hmax2s(a01, 4); a23 = hmax2s(a23, 4);
                    a01 = hmax2s(a01, 8); a23 = hmax2s(a23, 8);
                    if ((lane & 15) == m * 8) {
                        const int rl = ti * 128 + wr * 32 + m * 16 + ((lane >> 4) << 2);
                        const int strip = tj * 4 + wc * 2 + p;
                        unsigned k01 = mono2(__builtin_bit_cast(unsigned, a01));
                        unsigned k23 = mono2(__builtin_bit_cast(unsigned, a23));
                        unsigned short* dst = rowT + ((size_t)bx * NN + i0 + rl) * 16 + strip;
                        dst[0]  = (unsigned short)(k01 & 0xFFFFu);
                        dst[16] = (unsigned short)(k01 >> 16);
                        dst[32] = (unsigned short)(k23 & 0xFFFFu);
                        dst[48] = (unsigned short)(k23 >> 16);
                    }
                }
            }
            // --- col strip-maxes: strip = the wave's 32 rows ---
            {
                float rm[4];
                #pragma unroll
                for (int n = 0; n < 4; ++n) {
                    float x = fmaxf(max4(acc[0][n]), max4(acc[1][n]));
                    rm[n] = x;
                }
                h2 c01 = packh2(rm[0], rm[1]);
                h2 c23 = packh2(rm[2], rm[3]);
                c01 = hmax2s(c01, 16); c23 = hmax2s(c23, 16);
                c01 = hmax2s(c01, 32); c23 = hmax2s(c23, 32);
                if ((lane >> 4) == 0) {
                    const int strip = ti * 4 + wr;
                    const int cb = tj * 128 + wc * 64 + (lane & 15);
                    unsigned k01 = mono2(__builtin_bit_cast(unsigned, c01));
                    unsigned k23 = mono2(__builtin_bit_cast(unsigned, c23));
                    unsigned short* dst = colT + ((size_t)by * NN + j0 + cb) * 16 + strip;
                    dst[0]        = (unsigned short)(k01 & 0xFFFFu);   // col cb
                    dst[16 * 16]  = (unsigned short)(k01 >> 16);       // col cb+16
                    dst[32 * 16]  = (unsigned short)(k23 & 0xFFFFu);   // col cb+32
                    dst[48 * 16]  = (unsigned short)(k23 >> 16);       // col cb+48
                }
            }
        }
    }
}

// ---------------------------------------------------------------------------
// Kernel 3: per row/col, 10th-largest strip-max -> float lower-bound Tlb.
// Reads the [chunk][N][16] layout.
// ---------------------------------------------------------------------------
__global__ __launch_bounds__(256) void thresh_kernel(
        const unsigned short* __restrict__ rowT,
        const unsigned short* __restrict__ colT,
        float* __restrict__ Tlb_row, float* __restrict__ Tlb_col,
        unsigned* __restrict__ rowcnt, unsigned* __restrict__ colcnt) {
    const int t = blockIdx.x * 256 + threadIdx.x;
    const bool isRow = t < NN;
    const int idx = isRow ? t : t - NN;
    const unsigned short* src = isRow ? rowT : colT;

    unsigned lst[10];
    #pragma unroll
    for (int q = 0; q < 10; ++q) lst[q] = 0u;

    for (int c = 0; c < 32; ++c) {
        const uint4* p = reinterpret_cast<const uint4*>(src + ((size_t)c * NN + idx) * 16);
        #pragma unroll
        for (int hh = 0; hh < 2; ++hh) {
            uint4 q = p[hh];
            unsigned v0 = q.x & 0xFFFFu, v1 = q.x >> 16;
            unsigned v2 = q.y & 0xFFFFu, v3 = q.y >> 16;
            unsigned v4 = q.z & 0xFFFFu, v5 = q.z >> 16;
            unsigned v6 = q.w & 0xFFFFu, v7 = q.w >> 16;
            unsigned g01 = v0 > v1 ? v0 : v1, g23 = v2 > v3 ? v2 : v3;
            unsigned g45 = v4 > v5 ? v4 : v5, g67 = v6 > v7 ? v6 : v7;
            unsigned ga = g01 > g23 ? g01 : g23, gb = g45 > g67 ? g45 : g67;
            unsigned g = ga > gb ? ga : gb;
            if (g > lst[9]) {
                if (v0 > lst[9]) ins10(lst, v0);
                if (v1 > lst[9]) ins10(lst, v1);
                if (v2 > lst[9]) ins10(lst, v2);
                if (v3 > lst[9]) ins10(lst, v3);
                if (v4 > lst[9]) ins10(lst, v4);
                if (v5 > lst[9]) ins10(lst, v5);
                if (v6 > lst[9]) ins10(lst, v6);
                if (v7 > lst[9]) ins10(lst, v7);
            }
        }
    }
    float f = key2f16(lst[9]);
    float lb = f - fabsf(f) * 0.002f - 1e-6f;   // f16 ulp safety margin
    if (isRow) { Tlb_row[idx] = lb; rowcnt[idx] = 0u; }
    else       { Tlb_col[idx] = lb; colcnt[idx] = 0u; }
}

// ---------------------------------------------------------------------------
// Kernel 4 (pass B): GEMM + threshold filter; survivors via LDS stacks.
// 512 thr / 8 waves, 32x64 wave-tile. LDS ~78 KB -> 2 blocks/CU.
// ---------------------------------------------------------------------------
__global__ __launch_bounds__(512) void passB_kernel(
        const __hip_bfloat16* __restrict__ A, const __hip_bfloat16* __restrict__ Bm,
        const float* __restrict__ Tlb_row, const float* __restrict__ Tlb_col,
        unsigned* __restrict__ rowcnt, unsigned* __restrict__ colcnt,
        float* __restrict__ rowbuf, float* __restrict__ colbuf) {
    __shared__ __align__(16) char u_lds[65536];
    __shared__ float Trow_s[512];
    __shared__ float Tcol_s[512];
    __shared__ unsigned scnt[2];
    __shared__ uint2 sbuf[2][CAPL];

    const int tid = threadIdx.x;
    const int lane = tid & 63;
    const int w = tid >> 6;          // 0..7
    const int wr = w >> 1, wc = w & 1;
    int by, bx; xcd_map(blockIdx.x, by, bx);
    const int i0 = by * 512, j0 = bx * 512;

    Trow_s[tid] = Tlb_row[i0 + tid];
    Tcol_s[tid] = Tlb_col[j0 + tid];
    if (tid < 2) scnt[tid] = 0u;
    __syncthreads();

    for (int ti = 0; ti < 4; ++ti) {
        float trmin = 1e30f;
        #pragma unroll
        for (int m = 0; m < 2; ++m)
            #pragma unroll
            for (int r = 0; r < 4; ++r)
                trmin = fminf(trmin, Trow_s[ti * 128 + wr * 32 + m * 16 + ((lane >> 4) << 2) + r]);

        for (int tj = 0; tj < 4; ++tj) {
            f4v acc[2][4];
            #pragma unroll
            for (int m = 0; m < 2; ++m)
                #pragma unroll
                for (int n = 0; n < 4; ++n)
                    acc[m][n] = (f4v){0.f, 0.f, 0.f, 0.f};

            const __hip_bfloat16* Ab = A  + (size_t)(i0 + ti * 128) * DP;
            const __hip_bfloat16* Bb = Bm + (size_t)(j0 + tj * 128) * DP;

            KLOOP

            // filter epilogue: push survivors to LDS stacks
            float tc[4];
            #pragma unroll
            for (int n = 0; n < 4; ++n)
                tc[n] = Tcol_s[tj * 128 + wc * 64 + n * 16 + (lane & 15)];
            float tcmin = fminf(fminf(tc[0], tc[1]), fminf(tc[2], tc[3]));
            float vm = -1e30f;
            #pragma unroll
            for (int m = 0; m < 2; ++m)
                #pragma unroll
                for (int n = 0; n < 4; ++n)
                    vm = fmaxf(vm, max4(acc[m][n]));
            if (vm >= fminf(trmin, tcmin)) {
                #pragma unroll
                for (int m = 0; m < 2; ++m) {
                    #pragma unroll
                    for (int r = 0; r < 4; ++r) {
                        const int rl = ti * 128 + wr * 32 + m * 16 + ((lane >> 4) << 2) + r;
                        const float T = Trow_s[rl];
                        #pragma unroll
                        for (int n = 0; n < 4; ++n) {
                            const float v = acc[m][n][r];
                            if (v >= T) {
                                unsigned p = atomicAdd(&scnt[0], 1u);
                                if (p < CAPL) sbuf[0][p] = make_uint2((unsigned)(i0 + rl), __float_as_uint(v));
                                else { unsigned qq = atomicAdd(&rowcnt[i0 + rl], 1u);
                                       if (qq < CAP) rowbuf[(size_t)(i0 + rl) * CAP + qq] = v; }
                            }
                            if (v >= tc[n]) {
                                const int cn = j0 + tj * 128 + wc * 64 + n * 16 + (lane & 15);
                                unsigned p = atomicAdd(&scnt[1], 1u);
                                if (p < CAPL) sbuf[1][p] = make_uint2((unsigned)cn, __float_as_uint(v));
                                else { unsigned qq = atomicAdd(&colcnt[cn], 1u);
                                       if (qq < CAP) colbuf[(size_t)cn * CAP + qq] = v; }
                            }
                        }
                    }
                }
            }
        }
    }

    // parallel flush: independent global atomics, one latency round-trip
    __syncthreads();
    {
        const unsigned nr = scnt[0] < CAPL ? scnt[0] : CAPL;
        const unsigned nc = scnt[1] < CAPL ? scnt[1] : CAPL;
        for (unsigned i = tid; i < nr; i += 512) {
            uint2 e = sbuf[0][i];
            unsigned p = atomicAdd(&rowcnt[e.x], 1u);
            if (p < CAP) rowbuf[(size_t)e.x * CAP + p] = __uint_as_float(e.y);
        }
        for (unsigned i = tid; i < nc; i += 512) {
            uint2 e = sbuf[1][i];
            unsigned p = atomicAdd(&colcnt[e.x], 1u);
            if (p < CAP) colbuf[(size_t)e.x * CAP + p] = __uint_as_float(e.y);
        }
    }
}

// ---------------------------------------------------------------------------
// Kernel 5: exact top-10 of survivors -> rt / rs.
// ---------------------------------------------------------------------------
__global__ __launch_bounds__(256) void final_kernel(
        const unsigned* __restrict__ rowcnt, const unsigned* __restrict__ colcnt,
        const float* __restrict__ rowbuf, const float* __restrict__ colbuf,
        float* __restrict__ rt, float* __restrict__ rs) {
    const int t = blockIdx.x * 256 + threadIdx.x;
    const bool isRow = t < NN;
    const int idx = isRow ? t : t - NN;
    const unsigned cn = (isRow ? rowcnt : colcnt)[idx];
    const int n = (int)(cn < CAP ? cn : CAP);
    const float* buf = (isRow ? rowbuf : colbuf) + (size_t)idx * CAP;

    float lst[10];
    #pragma unroll
    for (int q = 0; q < 10; ++q) lst[q] = -1e30f;
    for (int i = 0; i < n; ++i) {
        float v = buf[i];
        if (v > lst[9]) ins10f(lst, v);
    }
    float s = 0.f;
    #pragma unroll
    for (int q = 0; q < 10; ++q) s += lst[q];
    s *= 0.1f;
    (isRow ? rt : rs)[idx] = s;
}

// ---------------------------------------------------------------------------
// Kernel 6: gathered dots + CSLS logits.
// ---------------------------------------------------------------------------
__global__ __launch_bounds__(256) void logits_kernel(
        const __hip_bfloat16* __restrict__ srcH, const __hip_bfloat16* __restrict__ tgtH,
        const int* __restrict__ sidx, const int* __restrict__ tidx,
        const float* __restrict__ rt, const float* __restrict__ rs,
        float* __restrict__ out) {
    const int b    = blockIdx.x;
    const int lane = threadIdx.x & 63;
    const int w    = threadIdx.x >> 6;

    const int s0 = sidx[b * KK];
    const int t0 = tidx[b * KK];
    float ps[5], pt[5];
    #pragma unroll
    for (int j = 0; j < 5; ++j) {
        int d = lane + 64 * j;
        ps[j] = __bfloat162float(srcH[(size_t)s0 * DP + d]);
        pt[j] = __bfloat162float(tgtH[(size_t)t0 * DP + d]);
    }
    const float rt_s0 = rt[s0];
    const float rs_t0 = rs[t0];

    for (int kk = w; kk < KK; kk += 4) {
        const int it = tidx[b * KK + kk];
        const int is = sidx[b * KK + kk];
        float a = 0.f, c = 0.f;
        #pragma unroll
        for (int j = 0; j < 5; ++j) {
            int d = lane + 64 * j;
            a += ps[j] * __bfloat162float(tgtH[(size_t)it * DP + d]);
            c += pt[j] * __bfloat162float(srcH[(size_t)is * DP + d]);
        }
        #pragma unroll
        for (int o = 32; o; o >>= 1) {
            a += __shfl_xor(a, o);
            c += __shfl_xor(c, o);
        }
        if (lane == 0) {
            out[b * KK + kk]           = 2.f * a - rt_s0 - rs[it];
            out[BB * KK + b * KK + kk] = 2.f * c - rs_t0 - rt[is];
        }
    }
}

// ---------------------------------------------------------------------------
extern "C" void kernel_launch(void* const* d_in, const int* in_sizes, int n_in,
                              void* d_out, int out_size, void* d_ws, size_t ws_size,
                              hipStream_t stream) {
    const float* nf_src = (const float*)d_in[0];
    const float* nf_tgt = (const float*)d_in[1];
    const int*   sidx   = (const int*)d_in[2];
    const int*   tidx   = (const int*)d_in[3];
    const float* svs    = (const float*)d_in[4];
    const float* tvs    = (const float*)d_in[5];

    char* ws = (char*)d_ws;
    const size_t SZ_H  = (size_t)NN * DP * 2;         // bf16 feats
    const size_t SZ_SM = (size_t)NN * 512 * 2;        // strip-maxes (16 MB each)
    __hip_bfloat16* srcH = (__hip_bfloat16*)ws;
    __hip_bfloat16* tgtH = (__hip_bfloat16*)(ws + SZ_H);
    unsigned short* rowT = (unsigned short*)(ws + 2 * SZ_H);
    unsigned short* colT = (unsigned short*)(ws + 2 * SZ_H + SZ_SM);
    // rowbuf/colbuf alias the rowT region (consumed by thresh before passB)
    float* rowbuf = (float*)(ws + 2 * SZ_H);
    float* colbuf = (float*)(ws + 2 * SZ_H + (size_t)NN * CAP * 4);
    char* tail = ws + 2 * SZ_H + 2 * SZ_SM;
    float* Tlb_row = (float*)(tail);
    float* Tlb_col = (float*)(tail + 65536);
    unsigned* rowcnt = (unsigned*)(tail + 2 * 65536);
    unsigned* colcnt = (unsigned*)(tail + 3 * 65536);
    float* rt = (float*)(tail + 4 * 65536);
    float* rs = (float*)(tail + 5 * 65536);

    tower_kernel<<<NN / 4, 256, 0, stream>>>(nf_src, svs, srcH);
    tower_kernel<<<NN / 4, 256, 0, stream>>>(nf_tgt, tvs, tgtH);
    passA_kernel<<<1024, 512, 0, stream>>>(srcH, tgtH, rowT, colT);
    thresh_kernel<<<(2 * NN) / 256, 256, 0, stream>>>(rowT, colT, Tlb_row, Tlb_col,
                                                      rowcnt, colcnt);
    passB_kernel<<<1024, 512, 0, stream>>>(srcH, tgtH, Tlb_row, Tlb_col,
                                           rowcnt, colcnt, rowbuf, colbuf);
    final_kernel<<<(2 * NN) / 256, 256, 0, stream>>>(rowcnt, colcnt, rowbuf, colbuf, rt, rs);
    logits_kernel<<<BB, 256, 0, stream>>>(srcH, tgtH, sidx, tidx, rt, rs, (float*)d_out);
}

// Round 21
// 632.327 us; speedup vs baseline: 1.3939x; 1.1120x over previous
//
#include <hip/hip_runtime.h>
#include <hip/hip_bf16.h>

#define NN 16384
#define DD 300
#define DP 320
#define RR 10
#define BB 1024
#define KK 64
#define CAP 128
#define CAPL 512   // per-block LDS survivor buffer entries per side

typedef __attribute__((ext_vector_type(8))) short s8v;   // 8 bf16 (4 VGPRs)
typedef __attribute__((ext_vector_type(4))) float f4v;   // MFMA accumulator
typedef _Float16 h2 __attribute__((ext_vector_type(2))); // packed fp16 pair

// ---- monotone f16 -> u16 key (order-preserving; packed 2 per dword) -------
__device__ __forceinline__ unsigned mono2(unsigned d) {
    unsigned s = ((d >> 15) & 0x10001u) * 0xFFFFu;
    return d ^ (s | 0x80008000u);
}
__device__ __forceinline__ float key2f16(unsigned k) {
    unsigned short b = (k & 0x8000u) ? (unsigned short)(k ^ 0x8000u)
                                     : (unsigned short)(~k & 0xFFFFu);
    _Float16 hv = __builtin_bit_cast(_Float16, b);
    return (float)hv;
}

__device__ __forceinline__ h2 h2max(h2 a, h2 b) {
    return __builtin_elementwise_max(a, b);
}
__device__ __forceinline__ h2 hmax2s(h2 a, int xb) {
    int x = __shfl_xor(__builtin_bit_cast(int, a), xb);
    return h2max(a, __builtin_bit_cast(h2, x));
}
__device__ __forceinline__ h2 packh2(float a, float b) {
    h2 r; r[0] = (_Float16)a; r[1] = (_Float16)b; return r;
}

// sorted-descending top-10 insert (unsigned keys)
__device__ __forceinline__ void ins10(unsigned (&lst)[10], unsigned v) {
    #pragma unroll
    for (int q = 0; q < 10; ++q) {
        unsigned a  = lst[q];
        unsigned mx = a > v ? a : v;
        v           = a > v ? v : a;
        lst[q] = mx;
    }
}
// float variant
__device__ __forceinline__ void ins10f(float (&lst)[10], float v) {
    #pragma unroll
    for (int q = 0; q < 10; ++q) {
        float a  = lst[q];
        float mx = fmaxf(a, v);
        v        = fminf(a, v);
        lst[q] = mx;
    }
}

// 2D XCD-chunked block mapping (round-10 win: FETCH 661->46 MB)
__device__ __forceinline__ void xcd_map(int bid, int& by, int& bx) {
    const int xcd = bid & 7;
    const int s   = bid >> 3;
    bx = (xcd << 2) | (s & 3);
    by = s >> 2;
}

__device__ __forceinline__ void gload_lds16(const void* g, void* l) {
#if __has_builtin(__builtin_amdgcn_global_load_lds)
    __builtin_amdgcn_global_load_lds(
        (const __attribute__((address_space(1))) void*)g,
        (__attribute__((address_space(3))) void*)l, 16, 0, 0);
#else
    const int lane = threadIdx.x & 63;
    int4 v = *reinterpret_cast<const int4*>(g);
    *reinterpret_cast<int4*>((char*)l + lane * 16) = v;
#endif
}

// Stage A[128][64] + B[128][64] bf16 into buffer `base` (A at +0, B at +16384).
// 16 waves: wave w stages rows w*8..w*8+7 of both. Linear LDS dest;
// XOR-preswizzled source: LDS[row][u] = G[row][u ^ (row&7)].
__device__ __forceinline__ void stage_tile(
        const __hip_bfloat16* __restrict__ Ab, const __hip_bfloat16* __restrict__ Bb,
        int kb, char* base, int w, int lane) {
    const int r8 = lane >> 3;
    const int u  = (lane & 7) ^ r8;
    const int row = w * 8 + r8;
    const size_t go = (size_t)row * DP + kb * 64 + u * 8;
    gload_lds16(Ab + go, base + w * 1024);
    gload_lds16(Bb + go, base + 16384 + w * 1024);
}

// ---------------------------------------------------------------------------
// Kernel 1: Householder tower + L2 normalize + bf16 cast (padded to 320).
// ---------------------------------------------------------------------------
__global__ __launch_bounds__(256) void tower_kernel(
        const float* __restrict__ feat, const float* __restrict__ vs,
        __hip_bfloat16* __restrict__ out) {
    __shared__ float vsh[RR * DD];
    const int tid = threadIdx.x;
    for (int i = tid; i < RR * DD; i += 256) vsh[i] = vs[i];
    __syncthreads();

    const int lane = tid & 63;
    const int wave = tid >> 6;
    const int row  = blockIdx.x * 4 + wave;

    float h[5];
    #pragma unroll
    for (int j = 0; j < 5; ++j) {
        int d = lane + 64 * j;
        h[j] = (d < DD) ? feat[(size_t)row * DD + d] : 0.f;
    }
    #pragma unroll
    for (int r = 0; r < RR; ++r) {
        float vl[5];
        float hv = 0.f, vv = 0.f;
        #pragma unroll
        for (int j = 0; j < 5; ++j) {
            int d = lane + 64 * j;
            float v = (d < DD) ? vsh[r * DD + d] : 0.f;
            vl[j] = v;
            hv += h[j] * v;
            vv += v * v;
        }
        #pragma unroll
        for (int o = 32; o; o >>= 1) {
            hv += __shfl_xor(hv, o);
            vv += __shfl_xor(vv, o);
        }
        float coef = hv / vv;
        #pragma unroll
        for (int j = 0; j < 5; ++j) h[j] -= coef * vl[j];
    }
    float nn = 0.f;
    #pragma unroll
    for (int j = 0; j < 5; ++j) nn += h[j] * h[j];
    #pragma unroll
    for (int o = 32; o; o >>= 1) nn += __shfl_xor(nn, o);
    float scale = 1.f / fmaxf(sqrtf(nn), 1e-12f);
    #pragma unroll
    for (int j = 0; j < 5; ++j) {
        int d = lane + 64 * j;
        float val = (d < DD) ? h[j] * scale : 0.f;
        out[(size_t)row * DP + d] = __float2bfloat16(val);
    }
}

// ---- pipelined K-loop (double-buffered, counted vmcnt, raw barriers) ------
// race-safety: stage(kb+1) writes buf[nxt]; last reads of buf[nxt] were
// compute(kb-1), separated by the trailing s_barrier of iteration kb-1.
// NOTE: no global stores occur inside this window (epilogues are LDS-only),
// so the counted vmcnt drains are exact (loads retire in issue order).
#define KLOOP(COMPUTE_BODY)                                                    \
    stage_tile(Ab, Bb, 0, u_lds, w, lane);                                     \
    _Pragma("unroll")                                                          \
    for (int kb = 0; kb < 5; ++kb) {                                           \
        char* curb = u_lds + (kb & 1) * 32768;                                 \
        if (kb < 4)                                                            \
            stage_tile(Ab, Bb, kb + 1, u_lds + ((kb + 1) & 1) * 32768, w, lane); \
        if (kb < 4) { asm volatile("s_waitcnt vmcnt(2)" ::: "memory"); }       \
        else        { asm volatile("s_waitcnt vmcnt(0)" ::: "memory"); }       \
        __builtin_amdgcn_s_barrier();                                          \
        asm volatile("" ::: "memory");                                         \
        {                                                                      \
            const __hip_bfloat16* Asub = (const __hip_bfloat16*)curb;          \
            const __hip_bfloat16* Bsub = (const __hip_bfloat16*)(curb + 16384);\
            COMPUTE_BODY                                                       \
        }                                                                      \
        asm volatile("" ::: "memory");                                         \
        __builtin_amdgcn_s_barrier();                                          \
    }

#define COMPUTE_TILE                                                           \
    _Pragma("unroll")                                                          \
    for (int ks = 0; ks < 2; ++ks) {                                           \
        s8v af[2], bfv[2];                                                     \
        const int ulog = ks * 4 + (lane >> 4);                                 \
        const int up   = ulog ^ (lane & 7);                                    \
        _Pragma("unroll")                                                      \
        for (int m = 0; m < 2; ++m) {                                          \
            const int row = wr * 32 + m * 16 + (lane & 15);                    \
            af[m] = *reinterpret_cast<const s8v*>(Asub + row * 64 + up * 8);   \
        }                                                                      \
        _Pragma("unroll")                                                      \
        for (int n = 0; n < 2; ++n) {                                          \
            const int row = wc * 32 + n * 16 + (lane & 15);                    \
            bfv[n] = *reinterpret_cast<const s8v*>(Bsub + row * 64 + up * 8);  \
        }                                                                      \
        _Pragma("unroll")                                                      \
        for (int m = 0; m < 2; ++m)                                            \
            _Pragma("unroll")                                                  \
            for (int n = 0; n < 2; ++n)                                        \
                acc[m][n] = __builtin_amdgcn_mfma_f32_16x16x32_bf16(           \
                    af[m], bfv[n], acc[m][n], 0, 0, 0);                        \
    }

// ---------------------------------------------------------------------------
// Kernel 2 (pass A): GEMM + strip-maxes. 1024 thr / 16 waves, 32x32
// wave-tile, pipelined staging. LDS 96 KB + strip arrays.
// ---------------------------------------------------------------------------
__global__ __launch_bounds__(1024) void passA_kernel(
        const __hip_bfloat16* __restrict__ A, const __hip_bfloat16* __restrict__ Bm,
        unsigned short* __restrict__ rowsmax_g,   // [N][512] u16 keys
        unsigned short* __restrict__ colsmax_g) { // [N][512] u16 keys
    __shared__ __align__(16) char u_lds[65536];   // 2 x (A|B 128x64)
    __shared__ unsigned short rowsm[16][512];
    __shared__ unsigned short colsm[512][16];

    const int tid = threadIdx.x;
    const int lane = tid & 63;
    const int w = tid >> 6;          // 0..15
    const int wr = w >> 2, wc = w & 3;
    int by, bx; xcd_map(blockIdx.x, by, bx);
    const int i0 = by * 512, j0 = bx * 512;

    for (int ti = 0; ti < 4; ++ti) {
        for (int tj = 0; tj < 4; ++tj) {
            f4v acc[2][2];
            #pragma unroll
            for (int m = 0; m < 2; ++m)
                #pragma unroll
                for (int n = 0; n < 2; ++n)
                    acc[m][n] = (f4v){0.f, 0.f, 0.f, 0.f};

            const __hip_bfloat16* Ab = A  + (size_t)(i0 + ti * 128) * DP;
            const __hip_bfloat16* Bb = Bm + (size_t)(j0 + tj * 128) * DP;

            KLOOP(COMPUTE_TILE)

            // --- row strip-max epilogue (strip = this wave's 32 cols) ---
            // C/D layout: col = lane&15, row = (lane>>4)*4 + reg
            #pragma unroll
            for (int m = 0; m < 2; ++m) {
                h2 a01 = h2max(packh2(acc[m][0][0], acc[m][0][1]),
                               packh2(acc[m][1][0], acc[m][1][1]));
                h2 a23 = h2max(packh2(acc[m][0][2], acc[m][0][3]),
                               packh2(acc[m][1][2], acc[m][1][3]));
                a01 = hmax2s(a01, 1); a23 = hmax2s(a23, 1);
                a01 = hmax2s(a01, 2); a23 = hmax2s(a23, 2);
                a01 = hmax2s(a01, 4); a23 = hmax2s(a23, 4);
                a01 = hmax2s(a01, 8); a23 = hmax2s(a23, 8);
                if ((lane & 15) == m * 8) {
                    const int rl = ti * 128 + wr * 32 + m * 16 + ((lane >> 4) << 2);
                    uint2 u = make_uint2(mono2(__builtin_bit_cast(unsigned, a01)),
                                         mono2(__builtin_bit_cast(unsigned, a23)));
                    *reinterpret_cast<uint2*>(&rowsm[tj * 4 + wc][rl]) = u;
                }
            }
            // --- col strip-max epilogue (strip = wave's 32 rows) ---
            {
                float rm0 = -1e30f, rm1 = -1e30f;
                #pragma unroll
                for (int m = 0; m < 2; ++m) {
                    rm0 = fmaxf(rm0, fmaxf(fmaxf(acc[m][0][0], acc[m][0][1]),
                                           fmaxf(acc[m][0][2], acc[m][0][3])));
                    rm1 = fmaxf(rm1, fmaxf(fmaxf(acc[m][1][0], acc[m][1][1]),
                                           fmaxf(acc[m][1][2], acc[m][1][3])));
                }
                h2 c = packh2(rm0, rm1);
                c = hmax2s(c, 16);
                c = hmax2s(c, 32);
                if ((lane >> 4) == 0) {
                    const int s = ti * 4 + wr;
                    const int cb = tj * 128 + wc * 32 + (lane & 15);
                    unsigned k = mono2(__builtin_bit_cast(unsigned, c));
                    colsm[cb][s]      = (unsigned short)(k & 0xFFFFu);
                    colsm[cb + 16][s] = (unsigned short)(k >> 16);
                }
            }
        }
    }
    __syncthreads();
    // flush strip-maxes: tid<512 rows, tid>=512 cols (parallel)
    if (tid < 512) {
        const int r = tid;
        unsigned short t16[16];
        #pragma unroll
        for (int s = 0; s < 16; ++s) t16[s] = rowsm[s][r];
        uint4 o0, o1;
        o0.x = t16[0] | ((unsigned)t16[1] << 16);  o0.y = t16[2] | ((unsigned)t16[3] << 16);
        o0.z = t16[4] | ((unsigned)t16[5] << 16);  o0.w = t16[6] | ((unsigned)t16[7] << 16);
        o1.x = t16[8] | ((unsigned)t16[9] << 16);  o1.y = t16[10] | ((unsigned)t16[11] << 16);
        o1.z = t16[12] | ((unsigned)t16[13] << 16); o1.w = t16[14] | ((unsigned)t16[15] << 16);
        uint4* rdst = reinterpret_cast<uint4*>(rowsmax_g + (size_t)(i0 + r) * 512 + bx * 16);
        rdst[0] = o0; rdst[1] = o1;
    } else {
        const int r = tid - 512;
        uint4 q0 = *reinterpret_cast<uint4*>(&colsm[r][0]);
        uint4 q1 = *reinterpret_cast<uint4*>(&colsm[r][8]);
        uint4* cdst = reinterpret_cast<uint4*>(colsmax_g + (size_t)(j0 + r) * 512 + by * 16);
        cdst[0] = q0; cdst[1] = q1;
    }
}

// ---------------------------------------------------------------------------
// Kernel 3: per row/col, 10th-largest strip-max -> float lower-bound Tlb.
// ---------------------------------------------------------------------------
__global__ __launch_bounds__(256) void thresh_kernel(
        const unsigned short* __restrict__ rowsmax_g,
        const unsigned short* __restrict__ colsmax_g,
        float* __restrict__ Tlb_row, float* __restrict__ Tlb_col,
        unsigned* __restrict__ rowcnt, unsigned* __restrict__ colcnt) {
    const int t = blockIdx.x * 256 + threadIdx.x;
    const bool isRow = t < NN;
    const int idx = isRow ? t : t - NN;
    const unsigned short* src = (isRow ? rowsmax_g : colsmax_g) + (size_t)idx * 512;

    unsigned lst[10];
    #pragma unroll
    for (int q = 0; q < 10; ++q) lst[q] = 0u;

    const uint4* p = reinterpret_cast<const uint4*>(src);
    for (int c = 0; c < 64; ++c) {
        uint4 q = p[c];
        unsigned v0 = q.x & 0xFFFFu, v1 = q.x >> 16;
        unsigned v2 = q.y & 0xFFFFu, v3 = q.y >> 16;
        unsigned v4 = q.z & 0xFFFFu, v5 = q.z >> 16;
        unsigned v6 = q.w & 0xFFFFu, v7 = q.w >> 16;
        unsigned g01 = v0 > v1 ? v0 : v1, g23 = v2 > v3 ? v2 : v3;
        unsigned g45 = v4 > v5 ? v4 : v5, g67 = v6 > v7 ? v6 : v7;
        unsigned ga = g01 > g23 ? g01 : g23, gb = g45 > g67 ? g45 : g67;
        unsigned g = ga > gb ? ga : gb;
        if (g > lst[9]) {
            if (v0 > lst[9]) ins10(lst, v0);
            if (v1 > lst[9]) ins10(lst, v1);
            if (v2 > lst[9]) ins10(lst, v2);
            if (v3 > lst[9]) ins10(lst, v3);
            if (v4 > lst[9]) ins10(lst, v4);
            if (v5 > lst[9]) ins10(lst, v5);
            if (v6 > lst[9]) ins10(lst, v6);
            if (v7 > lst[9]) ins10(lst, v7);
        }
    }
    float f = key2f16(lst[9]);
    float lb = f - fabsf(f) * 0.002f - 1e-6f;   // f16 ulp safety margin
    if (isRow) { Tlb_row[idx] = lb; rowcnt[idx] = 0u; }
    else       { Tlb_col[idx] = lb; colcnt[idx] = 0u; }
}

// ---------------------------------------------------------------------------
// Kernel 4 (pass B): GEMM + threshold filter; survivors via LDS stacks.
// Pipelined staging; LDS ~78 KB.
// ---------------------------------------------------------------------------
__global__ __launch_bounds__(1024) void passB_kernel(
        const __hip_bfloat16* __restrict__ A, const __hip_bfloat16* __restrict__ Bm,
        const float* __restrict__ Tlb_row, const float* __restrict__ Tlb_col,
        unsigned* __restrict__ rowcnt, unsigned* __restrict__ colcnt,
        float* __restrict__ rowbuf, float* __restrict__ colbuf) {
    __shared__ __align__(16) char u_lds[65536];
    __shared__ float Trow_s[512];
    __shared__ float Tcol_s[512];
    __shared__ unsigned scnt[2];
    __shared__ uint2 sbuf[2][CAPL];

    const int tid = threadIdx.x;
    const int lane = tid & 63;
    const int w = tid >> 6;          // 0..15
    const int wr = w >> 2, wc = w & 3;
    int by, bx; xcd_map(blockIdx.x, by, bx);
    const int i0 = by * 512, j0 = bx * 512;

    if (tid < 512) Trow_s[tid] = Tlb_row[i0 + tid];
    else           Tcol_s[tid - 512] = Tlb_col[j0 + tid - 512];
    if (tid < 2) scnt[tid] = 0u;
    __syncthreads();

    for (int ti = 0; ti < 4; ++ti) {
        float trmin = 1e30f;
        #pragma unroll
        for (int m = 0; m < 2; ++m)
            #pragma unroll
            for (int r = 0; r < 4; ++r)
                trmin = fminf(trmin, Trow_s[ti * 128 + wr * 32 + m * 16 + ((lane >> 4) << 2) + r]);

        for (int tj = 0; tj < 4; ++tj) {
            f4v acc[2][2];
            #pragma unroll
            for (int m = 0; m < 2; ++m)
                #pragma unroll
                for (int n = 0; n < 2; ++n)
                    acc[m][n] = (f4v){0.f, 0.f, 0.f, 0.f};

            const __hip_bfloat16* Ab = A  + (size_t)(i0 + ti * 128) * DP;
            const __hip_bfloat16* Bb = Bm + (size_t)(j0 + tj * 128) * DP;

            KLOOP(COMPUTE_TILE)

            // filter epilogue: push survivors to LDS stacks
            const int c0i = tj * 128 + wc * 32 + (lane & 15);
            const int c1i = c0i + 16;
            const float tc0 = Tcol_s[c0i], tc1 = Tcol_s[c1i];
            float vm = -1e30f;
            #pragma unroll
            for (int m = 0; m < 2; ++m) {
                float a = fmaxf(fmaxf(acc[m][0][0], acc[m][0][1]),
                                fmaxf(acc[m][0][2], acc[m][0][3]));
                float b = fmaxf(fmaxf(acc[m][1][0], acc[m][1][1]),
                                fmaxf(acc[m][1][2], acc[m][1][3]));
                vm = fmaxf(vm, fmaxf(a, b));
            }
            if (vm >= fminf(trmin, fminf(tc0, tc1))) {
                #pragma unroll
                for (int m = 0; m < 2; ++m) {
                    #pragma unroll
                    for (int r = 0; r < 4; ++r) {
                        const int rl = ti * 128 + wr * 32 + m * 16 + ((lane >> 4) << 2) + r;
                        const float T = Trow_s[rl];
                        const float v0 = acc[m][0][r], v1 = acc[m][1][r];
                        if (v0 >= T) {
                            unsigned p = atomicAdd(&scnt[0], 1u);
                            if (p < CAPL) sbuf[0][p] = make_uint2((unsigned)(i0 + rl), __float_as_uint(v0));
                            else { unsigned q = atomicAdd(&rowcnt[i0 + rl], 1u);
                                   if (q < CAP) rowbuf[(size_t)(i0 + rl) * CAP + q] = v0; }
                        }
                        if (v1 >= T) {
                            unsigned p = atomicAdd(&scnt[0], 1u);
                            if (p < CAPL) sbuf[0][p] = make_uint2((unsigned)(i0 + rl), __float_as_uint(v1));
                            else { unsigned q = atomicAdd(&rowcnt[i0 + rl], 1u);
                                   if (q < CAP) rowbuf[(size_t)(i0 + rl) * CAP + q] = v1; }
                        }
                        if (v0 >= tc0) {
                            unsigned p = atomicAdd(&scnt[1], 1u);
                            if (p < CAPL) sbuf[1][p] = make_uint2((unsigned)(j0 + c0i), __float_as_uint(v0));
                            else { unsigned q = atomicAdd(&colcnt[j0 + c0i], 1u);
                                   if (q < CAP) colbuf[(size_t)(j0 + c0i) * CAP + q] = v0; }
                        }
                        if (v1 >= tc1) {
                            unsigned p = atomicAdd(&scnt[1], 1u);
                            if (p < CAPL) sbuf[1][p] = make_uint2((unsigned)(j0 + c1i), __float_as_uint(v1));
                            else { unsigned q = atomicAdd(&colcnt[j0 + c1i], 1u);
                                   if (q < CAP) colbuf[(size_t)(j0 + c1i) * CAP + q] = v1; }
                        }
                    }
                }
            }
        }
    }

    // parallel flush: independent global atomics, one latency round-trip
    __syncthreads();
    {
        const unsigned nr = scnt[0] < CAPL ? scnt[0] : CAPL;
        const unsigned nc = scnt[1] < CAPL ? scnt[1] : CAPL;
        for (unsigned i = tid; i < nr; i += 1024) {
            uint2 e = sbuf[0][i];
            unsigned p = atomicAdd(&rowcnt[e.x], 1u);
            if (p < CAP) rowbuf[(size_t)e.x * CAP + p] = __uint_as_float(e.y);
        }
        for (unsigned i = tid; i < nc; i += 1024) {
            uint2 e = sbuf[1][i];
            unsigned p = atomicAdd(&colcnt[e.x], 1u);
            if (p < CAP) colbuf[(size_t)e.x * CAP + p] = __uint_as_float(e.y);
        }
    }
}

// ---------------------------------------------------------------------------
// Kernel 5: exact top-10 of survivors -> rt / rs.
// ---------------------------------------------------------------------------
__global__ __launch_bounds__(256) void final_kernel(
        const unsigned* __restrict__ rowcnt, const unsigned* __restrict__ colcnt,
        const float* __restrict__ rowbuf, const float* __restrict__ colbuf,
        float* __restrict__ rt, float* __restrict__ rs) {
    const int t = blockIdx.x * 256 + threadIdx.x;
    const bool isRow = t < NN;
    const int idx = isRow ? t : t - NN;
    const unsigned cn = (isRow ? rowcnt : colcnt)[idx];
    const int n = (int)(cn < CAP ? cn : CAP);
    const float* buf = (isRow ? rowbuf : colbuf) + (size_t)idx * CAP;

    float lst[10];
    #pragma unroll
    for (int q = 0; q < 10; ++q) lst[q] = -1e30f;
    for (int i = 0; i < n; ++i) {
        float v = buf[i];
        if (v > lst[9]) ins10f(lst, v);
    }
    float s = 0.f;
    #pragma unroll
    for (int q = 0; q < 10; ++q) s += lst[q];
    s *= 0.1f;
    (isRow ? rt : rs)[idx] = s;
}

// ---------------------------------------------------------------------------
// Kernel 6: gathered dots + CSLS logits.
// ---------------------------------------------------------------------------
__global__ __launch_bounds__(256) void logits_kernel(
        const __hip_bfloat16* __restrict__ srcH, const __hip_bfloat16* __restrict__ tgtH,
        const int* __restrict__ sidx, const int* __restrict__ tidx,
        const float* __restrict__ rt, const float* __restrict__ rs,
        float* __restrict__ out) {
    const int b    = blockIdx.x;
    const int lane = threadIdx.x & 63;
    const int w    = threadIdx.x >> 6;

    const int s0 = sidx[b * KK];
    const int t0 = tidx[b * KK];
    float ps[5], pt[5];
    #pragma unroll
    for (int j = 0; j < 5; ++j) {
        int d = lane + 64 * j;
        ps[j] = __bfloat162float(srcH[(size_t)s0 * DP + d]);
        pt[j] = __bfloat162float(tgtH[(size_t)t0 * DP + d]);
    }
    const float rt_s0 = rt[s0];
    const float rs_t0 = rs[t0];

    for (int kk = w; kk < KK; kk += 4) {
        const int it = tidx[b * KK + kk];
        const int is = sidx[b * KK + kk];
        float a = 0.f, c = 0.f;
        #pragma unroll
        for (int j = 0; j < 5; ++j) {
            int d = lane + 64 * j;
            a += ps[j] * __bfloat162float(tgtH[(size_t)it * DP + d]);
            c += pt[j] * __bfloat162float(srcH[(size_t)is * DP + d]);
        }
        #pragma unroll
        for (int o = 32; o; o >>= 1) {
            a += __shfl_xor(a, o);
            c += __shfl_xor(c, o);
        }
        if (lane == 0) {
            out[b * KK + kk]           = 2.f * a - rt_s0 - rs[it];
            out[BB * KK + b * KK + kk] = 2.f * c - rs_t0 - rt[is];
        }
    }
}

// ---------------------------------------------------------------------------
extern "C" void kernel_launch(void* const* d_in, const int* in_sizes, int n_in,
                              void* d_out, int out_size, void* d_ws, size_t ws_size,
                              hipStream_t stream) {
    const float* nf_src = (const float*)d_in[0];
    const float* nf_tgt = (const float*)d_in[1];
    const int*   sidx   = (const int*)d_in[2];
    const int*   tidx   = (const int*)d_in[3];
    const float* svs    = (const float*)d_in[4];
    const float* tvs    = (const float*)d_in[5];

    char* ws = (char*)d_ws;
    const size_t SZ_H  = (size_t)NN * DP * 2;         // bf16 feats
    const size_t SZ_SM = (size_t)NN * 512 * 2;        // strip-maxes
    __hip_bfloat16* srcH = (__hip_bfloat16*)ws;
    __hip_bfloat16* tgtH = (__hip_bfloat16*)(ws + SZ_H);
    unsigned short* rowsmax = (unsigned short*)(ws + 2 * SZ_H);
    unsigned short* colsmax = (unsigned short*)(ws + 2 * SZ_H + SZ_SM);
    // rowbuf/colbuf alias the rowsmax region (consumed by thresh before passB)
    float* rowbuf = (float*)(ws + 2 * SZ_H);
    float* colbuf = (float*)(ws + 2 * SZ_H + (size_t)NN * CAP * 4);
    char* tail = ws + 2 * SZ_H + 2 * SZ_SM;
    float* Tlb_row = (float*)(tail);
    float* Tlb_col = (float*)(tail + 65536);
    unsigned* rowcnt = (unsigned*)(tail + 2 * 65536);
    unsigned* colcnt = (unsigned*)(tail + 3 * 65536);
    float* rt = (float*)(tail + 4 * 65536);
    float* rs = (float*)(tail + 5 * 65536);

    tower_kernel<<<NN / 4, 256, 0, stream>>>(nf_src, svs, srcH);
    tower_kernel<<<NN / 4, 256, 0, stream>>>(nf_tgt, tvs, tgtH);
    passA_kernel<<<1024, 1024, 0, stream>>>(srcH, tgtH, rowsmax, colsmax);
    thresh_kernel<<<(2 * NN) / 256, 256, 0, stream>>>(rowsmax, colsmax, Tlb_row, Tlb_col,
                                                      rowcnt, colcnt);
    passB_kernel<<<1024, 1024, 0, stream>>>(srcH, tgtH, Tlb_row, Tlb_col,
                                            rowcnt, colcnt, rowbuf, colbuf);
    final_kernel<<<(2 * NN) / 256, 256, 0, stream>>>(rowcnt, colcnt, rowbuf, colbuf, rt, rs);
    logits_kernel<<<BB, 256, 0, stream>>>(srcH, tgtH, sidx, tidx, rt, rs, (float*)d_out);
}

// Round 22
// 616.692 us; speedup vs baseline: 1.4292x; 1.0254x over previous
//
#include <hip/hip_runtime.h>
#include <hip/hip_bf16.h>

#define NN 16384
#define DD 300
#define DP 320
#define RR 10
#define BB 1024
#define KK 64
#define CAP 128
#define CAPL 512    // per-block LDS survivor buffer entries per side
#define BUFSZ 49152 // A[128][64] + B0[128][64] + B1[128][64] bf16

typedef __attribute__((ext_vector_type(8))) short s8v;   // 8 bf16 (4 VGPRs)
typedef __attribute__((ext_vector_type(4))) float f4v;   // MFMA accumulator
typedef _Float16 h2 __attribute__((ext_vector_type(2))); // packed fp16 pair

// ---- monotone f16 -> u16 key (order-preserving; packed 2 per dword) -------
__device__ __forceinline__ unsigned mono2(unsigned d) {
    unsigned s = ((d >> 15) & 0x10001u) * 0xFFFFu;
    return d ^ (s | 0x80008000u);
}
__device__ __forceinline__ float key2f16(unsigned k) {
    unsigned short b = (k & 0x8000u) ? (unsigned short)(k ^ 0x8000u)
                                     : (unsigned short)(~k & 0xFFFFu);
    _Float16 hv = __builtin_bit_cast(_Float16, b);
    return (float)hv;
}

__device__ __forceinline__ h2 h2max(h2 a, h2 b) {
    return __builtin_elementwise_max(a, b);
}
__device__ __forceinline__ h2 hmax2s(h2 a, int xb) {
    int x = __shfl_xor(__builtin_bit_cast(int, a), xb);
    return h2max(a, __builtin_bit_cast(h2, x));
}
__device__ __forceinline__ h2 packh2(float a, float b) {
    h2 r; r[0] = (_Float16)a; r[1] = (_Float16)b; return r;
}

// sorted-descending top-10 insert (unsigned keys)
__device__ __forceinline__ void ins10(unsigned (&lst)[10], unsigned v) {
    #pragma unroll
    for (int q = 0; q < 10; ++q) {
        unsigned a  = lst[q];
        unsigned mx = a > v ? a : v;
        v           = a > v ? v : a;
        lst[q] = mx;
    }
}
// float variant
__device__ __forceinline__ void ins10f(float (&lst)[10], float v) {
    #pragma unroll
    for (int q = 0; q < 10; ++q) {
        float a  = lst[q];
        float mx = fmaxf(a, v);
        v        = fminf(a, v);
        lst[q] = mx;
    }
}

// 2D XCD-chunked block mapping (round-10 win: FETCH 661->46 MB)
__device__ __forceinline__ void xcd_map(int bid, int& by, int& bx) {
    const int xcd = bid & 7;
    const int s   = bid >> 3;
    bx = (xcd << 2) | (s & 3);
    by = s >> 2;
}

__device__ __forceinline__ void gload_lds16(const void* g, void* l) {
#if __has_builtin(__builtin_amdgcn_global_load_lds)
    __builtin_amdgcn_global_load_lds(
        (const __attribute__((address_space(1))) void*)g,
        (__attribute__((address_space(3))) void*)l, 16, 0, 0);
#else
    const int lane = threadIdx.x & 63;
    int4 v = *reinterpret_cast<const int4*>(g);
    *reinterpret_cast<int4*>((char*)l + lane * 16) = v;
#endif
}

// Stage A[128][64] + B0[128][64] + B1[128][64] bf16 into buffer `base`.
// 16 waves: wave w stages rows w*8..w*8+7 of all three (3 gload_lds).
// Linear LDS dest; XOR-preswizzled source: LDS[row][u] = G[row][u ^ (row&7)].
__device__ __forceinline__ void stage_tile2(
        const __hip_bfloat16* __restrict__ Ab,
        const __hip_bfloat16* __restrict__ Bb0,
        const __hip_bfloat16* __restrict__ Bb1,
        int kb, char* base, int w, int lane) {
    const int r8 = lane >> 3;
    const int u  = (lane & 7) ^ r8;
    const int row = w * 8 + r8;
    const size_t go = (size_t)row * DP + kb * 64 + u * 8;
    gload_lds16(Ab  + go, base + w * 1024);
    gload_lds16(Bb0 + go, base + 16384 + w * 1024);
    gload_lds16(Bb1 + go, base + 32768 + w * 1024);
}

// ---------------------------------------------------------------------------
// Kernel 1: Householder tower + L2 normalize + bf16 cast (padded to 320).
// ---------------------------------------------------------------------------
__global__ __launch_bounds__(256) void tower_kernel(
        const float* __restrict__ feat, const float* __restrict__ vs,
        __hip_bfloat16* __restrict__ out) {
    __shared__ float vsh[RR * DD];
    const int tid = threadIdx.x;
    for (int i = tid; i < RR * DD; i += 256) vsh[i] = vs[i];
    __syncthreads();

    const int lane = tid & 63;
    const int wave = tid >> 6;
    const int row  = blockIdx.x * 4 + wave;

    float h[5];
    #pragma unroll
    for (int j = 0; j < 5; ++j) {
        int d = lane + 64 * j;
        h[j] = (d < DD) ? feat[(size_t)row * DD + d] : 0.f;
    }
    #pragma unroll
    for (int r = 0; r < RR; ++r) {
        float vl[5];
        float hv = 0.f, vv = 0.f;
        #pragma unroll
        for (int j = 0; j < 5; ++j) {
            int d = lane + 64 * j;
            float v = (d < DD) ? vsh[r * DD + d] : 0.f;
            vl[j] = v;
            hv += h[j] * v;
            vv += v * v;
        }
        #pragma unroll
        for (int o = 32; o; o >>= 1) {
            hv += __shfl_xor(hv, o);
            vv += __shfl_xor(vv, o);
        }
        float coef = hv / vv;
        #pragma unroll
        for (int j = 0; j < 5; ++j) h[j] -= coef * vl[j];
    }
    float nn = 0.f;
    #pragma unroll
    for (int j = 0; j < 5; ++j) nn += h[j] * h[j];
    #pragma unroll
    for (int o = 32; o; o >>= 1) nn += __shfl_xor(nn, o);
    float scale = 1.f / fmaxf(sqrtf(nn), 1e-12f);
    #pragma unroll
    for (int j = 0; j < 5; ++j) {
        int d = lane + 64 * j;
        float val = (d < DD) ? h[j] * scale : 0.f;
        out[(size_t)row * DP + d] = __float2bfloat16(val);
    }
}

// ---- tj-paired pipelined K-loop (2-buffer, counted vmcnt, raw barriers) ---
// Identical sync skeleton to the verified round-16 KLOOP; 3 loads per stage.
// No global memory ops occur inside this window (epilogues are LDS-only).
#define KLOOP2                                                                 \
    stage_tile2(Ab, Bb0, Bb1, 0, u_lds, w, lane);                              \
    _Pragma("unroll")                                                          \
    for (int kb = 0; kb < 5; ++kb) {                                           \
        char* curb = u_lds + (kb & 1) * BUFSZ;                                 \
        if (kb < 4)                                                            \
            stage_tile2(Ab, Bb0, Bb1, kb + 1, u_lds + ((kb + 1) & 1) * BUFSZ, w, lane); \
        if (kb < 4) { asm volatile("s_waitcnt vmcnt(3)" ::: "memory"); }       \
        else        { asm volatile("s_waitcnt vmcnt(0)" ::: "memory"); }       \
        __builtin_amdgcn_s_barrier();                                          \
        asm volatile("" ::: "memory");                                         \
        {                                                                      \
            const __hip_bfloat16* Asub  = (const __hip_bfloat16*)curb;         \
            const __hip_bfloat16* B0sub = (const __hip_bfloat16*)(curb + 16384); \
            const __hip_bfloat16* B1sub = (const __hip_bfloat16*)(curb + 32768); \
            _Pragma("unroll")                                                  \
            for (int ks = 0; ks < 2; ++ks) {                                   \
                s8v af[2], bf0[2], bf1[2];                                     \
                const int ulog = ks * 4 + (lane >> 4);                         \
                const int up   = ulog ^ (lane & 7);                            \
                _Pragma("unroll")                                              \
                for (int m = 0; m < 2; ++m) {                                  \
                    const int row = wr * 32 + m * 16 + (lane & 15);            \
                    af[m] = *reinterpret_cast<const s8v*>(Asub + row * 64 + up * 8); \
                }                                                              \
                _Pragma("unroll")                                              \
                for (int n = 0; n < 2; ++n) {                                  \
                    const int row = wc * 32 + n * 16 + (lane & 15);            \
                    bf0[n] = *reinterpret_cast<const s8v*>(B0sub + row * 64 + up * 8); \
                    bf1[n] = *reinterpret_cast<const s8v*>(B1sub + row * 64 + up * 8); \
                }                                                              \
                _Pragma("unroll")                                              \
                for (int m = 0; m < 2; ++m)                                    \
                    _Pragma("unroll")                                          \
                    for (int n = 0; n < 2; ++n) {                              \
                        acc0[m][n] = __builtin_amdgcn_mfma_f32_16x16x32_bf16(  \
                            af[m], bf0[n], acc0[m][n], 0, 0, 0);               \
                        acc1[m][n] = __builtin_amdgcn_mfma_f32_16x16x32_bf16(  \
                            af[m], bf1[n], acc1[m][n], 0, 0, 0);               \
                    }                                                          \
            }                                                                  \
        }                                                                      \
        asm volatile("" ::: "memory");                                         \
        __builtin_amdgcn_s_barrier();                                          \
    }

// passA per-tile epilogue (row + col strip-maxes into LDS) for one acc/tj
#define ROWCOL_EPI(ACC, TJ)                                                    \
    _Pragma("unroll")                                                          \
    for (int m = 0; m < 2; ++m) {                                              \
        h2 a01 = h2max(packh2(ACC[m][0][0], ACC[m][0][1]),                     \
                       packh2(ACC[m][1][0], ACC[m][1][1]));                    \
        h2 a23 = h2max(packh2(ACC[m][0][2], ACC[m][0][3]),                     \
                       packh2(ACC[m][1][2], ACC[m][1][3]));                    \
        a01 = hmax2s(a01, 1); a23 = hmax2s(a23, 1);                            \
        a01 = hmax2s(a01, 2); a23 = hmax2s(a23, 2);                            \
        a01 = hmax2s(a01, 4); a23 = hmax2s(a23, 4);                            \
        a01 = hmax2s(a01, 8); a23 = hmax2s(a23, 8);                            \
        if ((lane & 15) == m * 8) {                                            \
            const int rl = ti * 128 + wr * 32 + m * 16 + ((lane >> 4) << 2);   \
            uint2 u = make_uint2(mono2(__builtin_bit_cast(unsigned, a01)),     \
                                 mono2(__builtin_bit_cast(unsigned, a23)));    \
            *reinterpret_cast<uint2*>(&rowsm[(TJ) * 4 + wc][rl]) = u;          \
        }                                                                      \
    }                                                                          \
    {                                                                          \
        float rm0 = -1e30f, rm1 = -1e30f;                                      \
        _Pragma("unroll")                                                      \
        for (int m = 0; m < 2; ++m) {                                          \
            rm0 = fmaxf(rm0, fmaxf(fmaxf(ACC[m][0][0], ACC[m][0][1]),          \
                                   fmaxf(ACC[m][0][2], ACC[m][0][3])));        \
            rm1 = fmaxf(rm1, fmaxf(fmaxf(ACC[m][1][0], ACC[m][1][1]),          \
                                   fmaxf(ACC[m][1][2], ACC[m][1][3])));        \
        }                                                                      \
        h2 c = packh2(rm0, rm1);                                               \
        c = hmax2s(c, 16);                                                     \
        c = hmax2s(c, 32);                                                     \
        if ((lane >> 4) == 0) {                                                \
            const int s = ti * 4 + wr;                                         \
            const int cb = (TJ) * 128 + wc * 32 + (lane & 15);                 \
            unsigned k = mono2(__builtin_bit_cast(unsigned, c));               \
            colsm[cb][s]      = (unsigned short)(k & 0xFFFFu);                 \
            colsm[cb + 16][s] = (unsigned short)(k >> 16);                     \
        }                                                                      \
    }

// ---------------------------------------------------------------------------
// Kernel 2 (pass A): GEMM + strip-maxes. 1024 thr / 16 waves, 32x32
// wave-tile, tj-paired. LDS 96 KB buffers + 32 KB strips = 128 KB.
// ---------------------------------------------------------------------------
__global__ __launch_bounds__(1024) void passA_kernel(
        const __hip_bfloat16* __restrict__ A, const __hip_bfloat16* __restrict__ Bm,
        unsigned short* __restrict__ rowsmax_g,   // [N][512] u16 keys
        unsigned short* __restrict__ colsmax_g) { // [N][512] u16 keys
    __shared__ __align__(16) char u_lds[2 * BUFSZ];   // 2 x (A|B0|B1)
    __shared__ unsigned short rowsm[16][512];
    __shared__ unsigned short colsm[512][16];

    const int tid = threadIdx.x;
    const int lane = tid & 63;
    const int w = tid >> 6;          // 0..15
    const int wr = w >> 2, wc = w & 3;
    int by, bx; xcd_map(blockIdx.x, by, bx);
    const int i0 = by * 512, j0 = bx * 512;

    for (int ti = 0; ti < 4; ++ti) {
        for (int tjp = 0; tjp < 2; ++tjp) {
            const int tj0 = tjp * 2, tj1 = tjp * 2 + 1;
            f4v acc0[2][2], acc1[2][2];
            #pragma unroll
            for (int m = 0; m < 2; ++m)
                #pragma unroll
                for (int n = 0; n < 2; ++n) {
                    acc0[m][n] = (f4v){0.f, 0.f, 0.f, 0.f};
                    acc1[m][n] = (f4v){0.f, 0.f, 0.f, 0.f};
                }

            const __hip_bfloat16* Ab  = A  + (size_t)(i0 + ti * 128) * DP;
            const __hip_bfloat16* Bb0 = Bm + (size_t)(j0 + tj0 * 128) * DP;
            const __hip_bfloat16* Bb1 = Bm + (size_t)(j0 + tj1 * 128) * DP;

            KLOOP2

            // C/D layout: col = lane&15, row = (lane>>4)*4 + reg
            ROWCOL_EPI(acc0, tj0)
            ROWCOL_EPI(acc1, tj1)
        }
    }
    __syncthreads();
    // flush strip-maxes: tid<512 rows, tid>=512 cols (parallel)
    if (tid < 512) {
        const int r = tid;
        unsigned short t16[16];
        #pragma unroll
        for (int s = 0; s < 16; ++s) t16[s] = rowsm[s][r];
        uint4 o0, o1;
        o0.x = t16[0] | ((unsigned)t16[1] << 16);  o0.y = t16[2] | ((unsigned)t16[3] << 16);
        o0.z = t16[4] | ((unsigned)t16[5] << 16);  o0.w = t16[6] | ((unsigned)t16[7] << 16);
        o1.x = t16[8] | ((unsigned)t16[9] << 16);  o1.y = t16[10] | ((unsigned)t16[11] << 16);
        o1.z = t16[12] | ((unsigned)t16[13] << 16); o1.w = t16[14] | ((unsigned)t16[15] << 16);
        uint4* rdst = reinterpret_cast<uint4*>(rowsmax_g + (size_t)(i0 + r) * 512 + bx * 16);
        rdst[0] = o0; rdst[1] = o1;
    } else {
        const int r = tid - 512;
        uint4 q0 = *reinterpret_cast<uint4*>(&colsm[r][0]);
        uint4 q1 = *reinterpret_cast<uint4*>(&colsm[r][8]);
        uint4* cdst = reinterpret_cast<uint4*>(colsmax_g + (size_t)(j0 + r) * 512 + by * 16);
        cdst[0] = q0; cdst[1] = q1;
    }
}

// ---------------------------------------------------------------------------
// Kernel 3: per row/col, 10th-largest strip-max -> float lower-bound Tlb.
// ---------------------------------------------------------------------------
__global__ __launch_bounds__(256) void thresh_kernel(
        const unsigned short* __restrict__ rowsmax_g,
        const unsigned short* __restrict__ colsmax_g,
        float* __restrict__ Tlb_row, float* __restrict__ Tlb_col,
        unsigned* __restrict__ rowcnt, unsigned* __restrict__ colcnt) {
    const int t = blockIdx.x * 256 + threadIdx.x;
    const bool isRow = t < NN;
    const int idx = isRow ? t : t - NN;
    const unsigned short* src = (isRow ? rowsmax_g : colsmax_g) + (size_t)idx * 512;

    unsigned lst[10];
    #pragma unroll
    for (int q = 0; q < 10; ++q) lst[q] = 0u;

    const uint4* p = reinterpret_cast<const uint4*>(src);
    for (int c = 0; c < 64; ++c) {
        uint4 q = p[c];
        unsigned v0 = q.x & 0xFFFFu, v1 = q.x >> 16;
        unsigned v2 = q.y & 0xFFFFu, v3 = q.y >> 16;
        unsigned v4 = q.z & 0xFFFFu, v5 = q.z >> 16;
        unsigned v6 = q.w & 0xFFFFu, v7 = q.w >> 16;
        unsigned g01 = v0 > v1 ? v0 : v1, g23 = v2 > v3 ? v2 : v3;
        unsigned g45 = v4 > v5 ? v4 : v5, g67 = v6 > v7 ? v6 : v7;
        unsigned ga = g01 > g23 ? g01 : g23, gb = g45 > g67 ? g45 : g67;
        unsigned g = ga > gb ? ga : gb;
        if (g > lst[9]) {
            if (v0 > lst[9]) ins10(lst, v0);
            if (v1 > lst[9]) ins10(lst, v1);
            if (v2 > lst[9]) ins10(lst, v2);
            if (v3 > lst[9]) ins10(lst, v3);
            if (v4 > lst[9]) ins10(lst, v4);
            if (v5 > lst[9]) ins10(lst, v5);
            if (v6 > lst[9]) ins10(lst, v6);
            if (v7 > lst[9]) ins10(lst, v7);
        }
    }
    float f = key2f16(lst[9]);
    float lb = f - fabsf(f) * 0.002f - 1e-6f;   // f16 ulp safety margin
    if (isRow) { Tlb_row[idx] = lb; rowcnt[idx] = 0u; }
    else       { Tlb_col[idx] = lb; colcnt[idx] = 0u; }
}

// passB per-tile filter epilogue for one acc/tj
#define FILTER_EPI(ACC, TJ)                                                    \
    {                                                                          \
        const int c0i = (TJ) * 128 + wc * 32 + (lane & 15);                    \
        const int c1i = c0i + 16;                                              \
        const float tc0 = Tcol_s[c0i], tc1 = Tcol_s[c1i];                      \
        float vm = -1e30f;                                                     \
        _Pragma("unroll")                                                      \
        for (int m = 0; m < 2; ++m) {                                          \
            float a = fmaxf(fmaxf(ACC[m][0][0], ACC[m][0][1]),                 \
                            fmaxf(ACC[m][0][2], ACC[m][0][3]));                \
            float b = fmaxf(fmaxf(ACC[m][1][0], ACC[m][1][1]),                 \
                            fmaxf(ACC[m][1][2], ACC[m][1][3]));                \
            vm = fmaxf(vm, fmaxf(a, b));                                       \
        }                                                                      \
        if (vm >= fminf(trmin, fminf(tc0, tc1))) {                             \
            _Pragma("unroll")                                                  \
            for (int m = 0; m < 2; ++m) {                                      \
                _Pragma("unroll")                                              \
                for (int r = 0; r < 4; ++r) {                                  \
                    const int rl = ti * 128 + wr * 32 + m * 16 + ((lane >> 4) << 2) + r; \
                    const float T = Trow_s[rl];                                \
                    const float v0 = ACC[m][0][r], v1 = ACC[m][1][r];          \
                    if (v0 >= T) {                                             \
                        unsigned p = atomicAdd(&scnt[0], 1u);                  \
                        if (p < CAPL) sbuf[0][p] = make_uint2((unsigned)(i0 + rl), __float_as_uint(v0)); \
                        else { unsigned q = atomicAdd(&rowcnt[i0 + rl], 1u);   \
                               if (q < CAP) rowbuf[(size_t)(i0 + rl) * CAP + q] = v0; } \
                    }                                                          \
                    if (v1 >= T) {                                             \
                        unsigned p = atomicAdd(&scnt[0], 1u);                  \
                        if (p < CAPL) sbuf[0][p] = make_uint2((unsigned)(i0 + rl), __float_as_uint(v1)); \
                        else { unsigned q = atomicAdd(&rowcnt[i0 + rl], 1u);   \
                               if (q < CAP) rowbuf[(size_t)(i0 + rl) * CAP + q] = v1; } \
                    }                                                          \
                    if (v0 >= tc0) {                                           \
                        unsigned p = atomicAdd(&scnt[1], 1u);                  \
                        if (p < CAPL) sbuf[1][p] = make_uint2((unsigned)(j0 + c0i), __float_as_uint(v0)); \
                        else { unsigned q = atomicAdd(&colcnt[j0 + c0i], 1u);  \
                               if (q < CAP) colbuf[(size_t)(j0 + c0i) * CAP + q] = v0; } \
                    }                                                          \
                    if (v1 >= tc1) {                                           \
                        unsigned p = atomicAdd(&scnt[1], 1u);                  \
                        if (p < CAPL) sbuf[1][p] = make_uint2((unsigned)(j0 + c1i), __float_as_uint(v1)); \
                        else { unsigned q = atomicAdd(&colcnt[j0 + c1i], 1u);  \
                               if (q < CAP) colbuf[(size_t)(j0 + c1i) * CAP + q] = v1; } \
                    }                                                          \
                }                                                              \
            }                                                                  \
        }                                                                      \
    }

// ---------------------------------------------------------------------------
// Kernel 4 (pass B): GEMM + threshold filter; survivors via LDS stacks.
// tj-paired pipelined staging; LDS ~106 KB.
// ---------------------------------------------------------------------------
__global__ __launch_bounds__(1024) void passB_kernel(
        const __hip_bfloat16* __restrict__ A, const __hip_bfloat16* __restrict__ Bm,
        const float* __restrict__ Tlb_row, const float* __restrict__ Tlb_col,
        unsigned* __restrict__ rowcnt, unsigned* __restrict__ colcnt,
        float* __restrict__ rowbuf, float* __restrict__ colbuf) {
    __shared__ __align__(16) char u_lds[2 * BUFSZ];
    __shared__ float Trow_s[512];
    __shared__ float Tcol_s[512];
    __shared__ unsigned scnt[2];
    __shared__ uint2 sbuf[2][CAPL];

    const int tid = threadIdx.x;
    const int lane = tid & 63;
    const int w = tid >> 6;          // 0..15
    const int wr = w >> 2, wc = w & 3;
    int by, bx; xcd_map(blockIdx.x, by, bx);
    const int i0 = by * 512, j0 = bx * 512;

    if (tid < 512) Trow_s[tid] = Tlb_row[i0 + tid];
    else           Tcol_s[tid - 512] = Tlb_col[j0 + tid - 512];
    if (tid < 2) scnt[tid] = 0u;
    __syncthreads();

    for (int ti = 0; ti < 4; ++ti) {
        float trmin = 1e30f;
        #pragma unroll
        for (int m = 0; m < 2; ++m)
            #pragma unroll
            for (int r = 0; r < 4; ++r)
                trmin = fminf(trmin, Trow_s[ti * 128 + wr * 32 + m * 16 + ((lane >> 4) << 2) + r]);

        for (int tjp = 0; tjp < 2; ++tjp) {
            const int tj0 = tjp * 2, tj1 = tjp * 2 + 1;
            f4v acc0[2][2], acc1[2][2];
            #pragma unroll
            for (int m = 0; m < 2; ++m)
                #pragma unroll
                for (int n = 0; n < 2; ++n) {
                    acc0[m][n] = (f4v){0.f, 0.f, 0.f, 0.f};
                    acc1[m][n] = (f4v){0.f, 0.f, 0.f, 0.f};
                }

            const __hip_bfloat16* Ab  = A  + (size_t)(i0 + ti * 128) * DP;
            const __hip_bfloat16* Bb0 = Bm + (size_t)(j0 + tj0 * 128) * DP;
            const __hip_bfloat16* Bb1 = Bm + (size_t)(j0 + tj1 * 128) * DP;

            KLOOP2

            FILTER_EPI(acc0, tj0)
            FILTER_EPI(acc1, tj1)
        }
    }

    // parallel flush: independent global atomics, one latency round-trip
    __syncthreads();
    {
        const unsigned nr = scnt[0] < CAPL ? scnt[0] : CAPL;
        const unsigned nc = scnt[1] < CAPL ? scnt[1] : CAPL;
        for (unsigned i = tid; i < nr; i += 1024) {
            uint2 e = sbuf[0][i];
            unsigned p = atomicAdd(&rowcnt[e.x], 1u);
            if (p < CAP) rowbuf[(size_t)e.x * CAP + p] = __uint_as_float(e.y);
        }
        for (unsigned i = tid; i < nc; i += 1024) {
            uint2 e = sbuf[1][i];
            unsigned p = atomicAdd(&colcnt[e.x], 1u);
            if (p < CAP) colbuf[(size_t)e.x * CAP + p] = __uint_as_float(e.y);
        }
    }
}

// ---------------------------------------------------------------------------
// Kernel 5: exact top-10 of survivors -> rt / rs.
// ---------------------------------------------------------------------------
__global__ __launch_bounds__(256) void final_kernel(
        const unsigned* __restrict__ rowcnt, const unsigned* __restrict__ colcnt,
        const float* __restrict__ rowbuf, const float* __restrict__ colbuf,
        float* __restrict__ rt, float* __restrict__ rs) {
    const int t = blockIdx.x * 256 + threadIdx.x;
    const bool isRow = t < NN;
    const int idx = isRow ? t : t - NN;
    const unsigned cn = (isRow ? rowcnt : colcnt)[idx];
    const int n = (int)(cn < CAP ? cn : CAP);
    const float* buf = (isRow ? rowbuf : colbuf) + (size_t)idx * CAP;

    float lst[10];
    #pragma unroll
    for (int q = 0; q < 10; ++q) lst[q] = -1e30f;
    for (int i = 0; i < n; ++i) {
        float v = buf[i];
        if (v > lst[9]) ins10f(lst, v);
    }
    float s = 0.f;
    #pragma unroll
    for (int q = 0; q < 10; ++q) s += lst[q];
    s *= 0.1f;
    (isRow ? rt : rs)[idx] = s;
}

// ---------------------------------------------------------------------------
// Kernel 6: gathered dots + CSLS logits.
// ---------------------------------------------------------------------------
__global__ __launch_bounds__(256) void logits_kernel(
        const __hip_bfloat16* __restrict__ srcH, const __hip_bfloat16* __restrict__ tgtH,
        const int* __restrict__ sidx, const int* __restrict__ tidx,
        const float* __restrict__ rt, const float* __restrict__ rs,
        float* __restrict__ out) {
    const int b    = blockIdx.x;
    const int lane = threadIdx.x & 63;
    const int w    = threadIdx.x >> 6;

    const int s0 = sidx[b * KK];
    const int t0 = tidx[b * KK];
    float ps[5], pt[5];
    #pragma unroll
    for (int j = 0; j < 5; ++j) {
        int d = lane + 64 * j;
        ps[j] = __bfloat162float(srcH[(size_t)s0 * DP + d]);
        pt[j] = __bfloat162float(tgtH[(size_t)t0 * DP + d]);
    }
    const float rt_s0 = rt[s0];
    const float rs_t0 = rs[t0];

    for (int kk = w; kk < KK; kk += 4) {
        const int it = tidx[b * KK + kk];
        const int is = sidx[b * KK + kk];
        float a = 0.f, c = 0.f;
        #pragma unroll
        for (int j = 0; j < 5; ++j) {
            int d = lane + 64 * j;
            a += ps[j] * __bfloat162float(tgtH[(size_t)it * DP + d]);
            c += pt[j] * __bfloat162float(srcH[(size_t)is * DP + d]);
        }
        #pragma unroll
        for (int o = 32; o; o >>= 1) {
            a += __shfl_xor(a, o);
            c += __shfl_xor(c, o);
        }
        if (lane == 0) {
            out[b * KK + kk]           = 2.f * a - rt_s0 - rs[it];
            out[BB * KK + b * KK + kk] = 2.f * c - rs_t0 - rt[is];
        }
    }
}

// ---------------------------------------------------------------------------
extern "C" void kernel_launch(void* const* d_in, const int* in_sizes, int n_in,
                              void* d_out, int out_size, void* d_ws, size_t ws_size,
                              hipStream_t stream) {
    const float* nf_src = (const float*)d_in[0];
    const float* nf_tgt = (const float*)d_in[1];
    const int*   sidx   = (const int*)d_in[2];
    const int*   tidx   = (const int*)d_in[3];
    const float* svs    = (const float*)d_in[4];
    const float* tvs    = (const float*)d_in[5];

    char* ws = (char*)d_ws;
    const size_t SZ_H  = (size_t)NN * DP * 2;         // bf16 feats
    const size_t SZ_SM = (size_t)NN * 512 * 2;        // strip-maxes
    __hip_bfloat16* srcH = (__hip_bfloat16*)ws;
    __hip_bfloat16* tgtH = (__hip_bfloat16*)(ws + SZ_H);
    unsigned short* rowsmax = (unsigned short*)(ws + 2 * SZ_H);
    unsigned short* colsmax = (unsigned short*)(ws + 2 * SZ_H + SZ_SM);
    // rowbuf/colbuf alias the rowsmax region (consumed by thresh before passB)
    float* rowbuf = (float*)(ws + 2 * SZ_H);
    float* colbuf = (float*)(ws + 2 * SZ_H + (size_t)NN * CAP * 4);
    char* tail = ws + 2 * SZ_H + 2 * SZ_SM;
    float* Tlb_row = (float*)(tail);
    float* Tlb_col = (float*)(tail + 65536);
    unsigned* rowcnt = (unsigned*)(tail + 2 * 65536);
    unsigned* colcnt = (unsigned*)(tail + 3 * 65536);
    float* rt = (float*)(tail + 4 * 65536);
    float* rs = (float*)(tail + 5 * 65536);

    tower_kernel<<<NN / 4, 256, 0, stream>>>(nf_src, svs, srcH);
    tower_kernel<<<NN / 4, 256, 0, stream>>>(nf_tgt, tvs, tgtH);
    passA_kernel<<<1024, 1024, 0, stream>>>(srcH, tgtH, rowsmax, colsmax);
    thresh_kernel<<<(2 * NN) / 256, 256, 0, stream>>>(rowsmax, colsmax, Tlb_row, Tlb_col,
                                                      rowcnt, colcnt);
    passB_kernel<<<1024, 1024, 0, stream>>>(srcH, tgtH, Tlb_row, Tlb_col,
                                            rowcnt, colcnt, rowbuf, colbuf);
    final_kernel<<<(2 * NN) / 256, 256, 0, stream>>>(rowcnt, colcnt, rowbuf, colbuf, rt, rs);
    logits_kernel<<<BB, 256, 0, stream>>>(srcH, tgtH, sidx, tidx, rt, rs, (float*)d_out);
}

// Round 23
// 599.060 us; speedup vs baseline: 1.4713x; 1.0294x over previous
//
#include <hip/hip_runtime.h>
#include <hip/hip_bf16.h>

#define NN 16384
#define DD 300
#define DP 320
#define RR 10
#define BB 1024
#define KK 64
#define CAP 128
#define CAPL 512    // per-block LDS survivor buffer entries per side
#define BUFSZ 49152 // A[128][64] + B0[128][64] + B1[128][64] bf16

typedef __attribute__((ext_vector_type(8))) short s8v;   // 8 bf16 (4 VGPRs)
typedef __attribute__((ext_vector_type(4))) float f4v;   // MFMA accumulator
typedef _Float16 h2 __attribute__((ext_vector_type(2))); // packed fp16 pair

// ---- monotone f16 -> u16 key (order-preserving; packed 2 per dword) -------
__device__ __forceinline__ unsigned mono2(unsigned d) {
    unsigned s = ((d >> 15) & 0x10001u) * 0xFFFFu;
    return d ^ (s | 0x80008000u);
}
__device__ __forceinline__ float key2f16(unsigned k) {
    unsigned short b = (k & 0x8000u) ? (unsigned short)(k ^ 0x8000u)
                                     : (unsigned short)(~k & 0xFFFFu);
    _Float16 hv = __builtin_bit_cast(_Float16, b);
    return (float)hv;
}

__device__ __forceinline__ h2 h2max(h2 a, h2 b) {
    return __builtin_elementwise_max(a, b);
}
__device__ __forceinline__ h2 hmax2s(h2 a, int xb) {
    int x = __shfl_xor(__builtin_bit_cast(int, a), xb);
    return h2max(a, __builtin_bit_cast(h2, x));
}
__device__ __forceinline__ h2 packh2(float a, float b) {
    h2 r; r[0] = (_Float16)a; r[1] = (_Float16)b; return r;
}

// sorted-descending top-10 insert (unsigned keys)
__device__ __forceinline__ void ins10(unsigned (&lst)[10], unsigned v) {
    #pragma unroll
    for (int q = 0; q < 10; ++q) {
        unsigned a  = lst[q];
        unsigned mx = a > v ? a : v;
        v           = a > v ? v : a;
        lst[q] = mx;
    }
}
// float variant
__device__ __forceinline__ void ins10f(float (&lst)[10], float v) {
    #pragma unroll
    for (int q = 0; q < 10; ++q) {
        float a  = lst[q];
        float mx = fmaxf(a, v);
        v        = fminf(a, v);
        lst[q] = mx;
    }
}

// 2D XCD-chunked block mapping (round-10 win: FETCH 661->46 MB)
__device__ __forceinline__ void xcd_map(int bid, int& by, int& bx) {
    const int xcd = bid & 7;
    const int s   = bid >> 3;
    bx = (xcd << 2) | (s & 3);
    by = s >> 2;
}

__device__ __forceinline__ void gload_lds16(const void* g, void* l) {
#if __has_builtin(__builtin_amdgcn_global_load_lds)
    __builtin_amdgcn_global_load_lds(
        (const __attribute__((address_space(1))) void*)g,
        (__attribute__((address_space(3))) void*)l, 16, 0, 0);
#else
    const int lane = threadIdx.x & 63;
    int4 v = *reinterpret_cast<const int4*>(g);
    *reinterpret_cast<int4*>((char*)l + lane * 16) = v;
#endif
}

// Stage A[128][64] + B0[128][64] + B1[128][64] bf16 into buffer `base`.
// 16 waves: wave w stages rows w*8..w*8+7 of all three (3 gload_lds).
// Linear LDS dest; XOR-preswizzled source: LDS[row][u] = G[row][u ^ (row&7)].
__device__ __forceinline__ void stage_tile2(
        const __hip_bfloat16* __restrict__ Ab,
        const __hip_bfloat16* __restrict__ Bb0,
        const __hip_bfloat16* __restrict__ Bb1,
        int kb, char* base, int w, int lane) {
    const int r8 = lane >> 3;
    const int u  = (lane & 7) ^ r8;
    const int row = w * 8 + r8;
    const size_t go = (size_t)row * DP + kb * 64 + u * 8;
    gload_lds16(Ab  + go, base + w * 1024);
    gload_lds16(Bb0 + go, base + 16384 + w * 1024);
    gload_lds16(Bb1 + go, base + 32768 + w * 1024);
}

// ---------------------------------------------------------------------------
// Kernel 1: Householder tower + L2 normalize + bf16 cast (padded to 320).
// ---------------------------------------------------------------------------
__global__ __launch_bounds__(256) void tower_kernel(
        const float* __restrict__ feat, const float* __restrict__ vs,
        __hip_bfloat16* __restrict__ out) {
    __shared__ float vsh[RR * DD];
    const int tid = threadIdx.x;
    for (int i = tid; i < RR * DD; i += 256) vsh[i] = vs[i];
    __syncthreads();

    const int lane = tid & 63;
    const int wave = tid >> 6;
    const int row  = blockIdx.x * 4 + wave;

    float h[5];
    #pragma unroll
    for (int j = 0; j < 5; ++j) {
        int d = lane + 64 * j;
        h[j] = (d < DD) ? feat[(size_t)row * DD + d] : 0.f;
    }
    #pragma unroll
    for (int r = 0; r < RR; ++r) {
        float vl[5];
        float hv = 0.f, vv = 0.f;
        #pragma unroll
        for (int j = 0; j < 5; ++j) {
            int d = lane + 64 * j;
            float v = (d < DD) ? vsh[r * DD + d] : 0.f;
            vl[j] = v;
            hv += h[j] * v;
            vv += v * v;
        }
        #pragma unroll
        for (int o = 32; o; o >>= 1) {
            hv += __shfl_xor(hv, o);
            vv += __shfl_xor(vv, o);
        }
        float coef = hv / vv;
        #pragma unroll
        for (int j = 0; j < 5; ++j) h[j] -= coef * vl[j];
    }
    float nn = 0.f;
    #pragma unroll
    for (int j = 0; j < 5; ++j) nn += h[j] * h[j];
    #pragma unroll
    for (int o = 32; o; o >>= 1) nn += __shfl_xor(nn, o);
    float scale = 1.f / fmaxf(sqrtf(nn), 1e-12f);
    #pragma unroll
    for (int j = 0; j < 5; ++j) {
        int d = lane + 64 * j;
        float val = (d < DD) ? h[j] * scale : 0.f;
        out[(size_t)row * DP + d] = __float2bfloat16(val);
    }
}

// ---- tj-paired pipelined K-loop (2-buffer, counted vmcnt, raw barriers) ---
// Sequenced frag use (bf1 loaded AFTER acc0's MFMAs consume bf0): peak frag
// liveness 16 VGPR instead of 24 -> no scratch spill at 16-wave residency.
// No global memory ops inside this window (epilogues are LDS-only).
#define KLOOP2                                                                 \
    stage_tile2(Ab, Bb0, Bb1, 0, u_lds, w, lane);                              \
    _Pragma("unroll")                                                          \
    for (int kb = 0; kb < 5; ++kb) {                                           \
        char* curb = u_lds + (kb & 1) * BUFSZ;                                 \
        if (kb < 4)                                                            \
            stage_tile2(Ab, Bb0, Bb1, kb + 1, u_lds + ((kb + 1) & 1) * BUFSZ, w, lane); \
        if (kb < 4) { asm volatile("s_waitcnt vmcnt(3)" ::: "memory"); }       \
        else        { asm volatile("s_waitcnt vmcnt(0)" ::: "memory"); }       \
        __builtin_amdgcn_s_barrier();                                          \
        asm volatile("" ::: "memory");                                         \
        {                                                                      \
            const __hip_bfloat16* Asub  = (const __hip_bfloat16*)curb;         \
            const __hip_bfloat16* B0sub = (const __hip_bfloat16*)(curb + 16384); \
            const __hip_bfloat16* B1sub = (const __hip_bfloat16*)(curb + 32768); \
            _Pragma("unroll")                                                  \
            for (int ks = 0; ks < 2; ++ks) {                                   \
                const int ulog = ks * 4 + (lane >> 4);                         \
                const int up   = ulog ^ (lane & 7);                            \
                s8v af[2];                                                     \
                _Pragma("unroll")                                              \
                for (int m = 0; m < 2; ++m) {                                  \
                    const int row = wr * 32 + m * 16 + (lane & 15);            \
                    af[m] = *reinterpret_cast<const s8v*>(Asub + row * 64 + up * 8); \
                }                                                              \
                {                                                              \
                    s8v bf0[2];                                                \
                    _Pragma("unroll")                                          \
                    for (int n = 0; n < 2; ++n) {                              \
                        const int row = wc * 32 + n * 16 + (lane & 15);        \
                        bf0[n] = *reinterpret_cast<const s8v*>(B0sub + row * 64 + up * 8); \
                    }                                                          \
                    _Pragma("unroll")                                          \
                    for (int m = 0; m < 2; ++m)                                \
                        _Pragma("unroll")                                      \
                        for (int n = 0; n < 2; ++n)                            \
                            acc0[m][n] = __builtin_amdgcn_mfma_f32_16x16x32_bf16( \
                                af[m], bf0[n], acc0[m][n], 0, 0, 0);           \
                }                                                              \
                {                                                              \
                    s8v bf1[2];                                                \
                    _Pragma("unroll")                                          \
                    for (int n = 0; n < 2; ++n) {                              \
                        const int row = wc * 32 + n * 16 + (lane & 15);        \
                        bf1[n] = *reinterpret_cast<const s8v*>(B1sub + row * 64 + up * 8); \
                    }                                                          \
                    _Pragma("unroll")                                          \
                    for (int m = 0; m < 2; ++m)                                \
                        _Pragma("unroll")                                      \
                        for (int n = 0; n < 2; ++n)                            \
                            acc1[m][n] = __builtin_amdgcn_mfma_f32_16x16x32_bf16( \
                                af[m], bf1[n], acc1[m][n], 0, 0, 0);           \
                }                                                              \
            }                                                                  \
        }                                                                      \
        asm volatile("" ::: "memory");                                         \
        __builtin_amdgcn_s_barrier();                                          \
    }

// passA per-tile epilogue (row + col strip-maxes into LDS) for one acc/tj
#define ROWCOL_EPI(ACC, TJ)                                                    \
    _Pragma("unroll")                                                          \
    for (int m = 0; m < 2; ++m) {                                              \
        h2 a01 = h2max(packh2(ACC[m][0][0], ACC[m][0][1]),                     \
                       packh2(ACC[m][1][0], ACC[m][1][1]));                    \
        h2 a23 = h2max(packh2(ACC[m][0][2], ACC[m][0][3]),                     \
                       packh2(ACC[m][1][2], ACC[m][1][3]));                    \
        a01 = hmax2s(a01, 1); a23 = hmax2s(a23, 1);                            \
        a01 = hmax2s(a01, 2); a23 = hmax2s(a23, 2);                            \
        a01 = hmax2s(a01, 4); a23 = hmax2s(a23, 4);                            \
        a01 = hmax2s(a01, 8); a23 = hmax2s(a23, 8);                            \
        if ((lane & 15) == m * 8) {                                            \
            const int rl = ti * 128 + wr * 32 + m * 16 + ((lane >> 4) << 2);   \
            uint2 u = make_uint2(mono2(__builtin_bit_cast(unsigned, a01)),     \
                                 mono2(__builtin_bit_cast(unsigned, a23)));    \
            *reinterpret_cast<uint2*>(&rowsm[(TJ) * 4 + wc][rl]) = u;          \
        }                                                                      \
    }                                                                          \
    {                                                                          \
        float rm0 = -1e30f, rm1 = -1e30f;                                      \
        _Pragma("unroll")                                                      \
        for (int m = 0; m < 2; ++m) {                                          \
            rm0 = fmaxf(rm0, fmaxf(fmaxf(ACC[m][0][0], ACC[m][0][1]),          \
                                   fmaxf(ACC[m][0][2], ACC[m][0][3])));        \
            rm1 = fmaxf(rm1, fmaxf(fmaxf(ACC[m][1][0], ACC[m][1][1]),          \
                                   fmaxf(ACC[m][1][2], ACC[m][1][3])));        \
        }                                                                      \
        h2 c = packh2(rm0, rm1);                                               \
        c = hmax2s(c, 16);                                                     \
        c = hmax2s(c, 32);                                                     \
        if ((lane >> 4) == 0) {                                                \
            const int s = ti * 4 + wr;                                         \
            const int cb = (TJ) * 128 + wc * 32 + (lane & 15);                 \
            unsigned k = mono2(__builtin_bit_cast(unsigned, c));               \
            colsm[cb][s]      = (unsigned short)(k & 0xFFFFu);                 \
            colsm[cb + 16][s] = (unsigned short)(k >> 16);                     \
        }                                                                      \
    }

// ---------------------------------------------------------------------------
// Kernel 2 (pass A): GEMM + strip-maxes. 1024 thr / 16 waves, 32x32
// wave-tile, tj-paired. LDS 96 KB buffers + 32 KB strips = 128 KB.
// ---------------------------------------------------------------------------
__global__ __launch_bounds__(1024) void passA_kernel(
        const __hip_bfloat16* __restrict__ A, const __hip_bfloat16* __restrict__ Bm,
        unsigned short* __restrict__ rowsmax_g,   // [N][512] u16 keys
        unsigned short* __restrict__ colsmax_g) { // [N][512] u16 keys
    __shared__ __align__(16) char u_lds[2 * BUFSZ];   // 2 x (A|B0|B1)
    __shared__ unsigned short rowsm[16][512];
    __shared__ unsigned short colsm[512][16];

    const int tid = threadIdx.x;
    const int lane = tid & 63;
    const int w = tid >> 6;          // 0..15
    const int wr = w >> 2, wc = w & 3;
    int by, bx; xcd_map(blockIdx.x, by, bx);
    const int i0 = by * 512, j0 = bx * 512;

    for (int ti = 0; ti < 4; ++ti) {
        for (int tjp = 0; tjp < 2; ++tjp) {
            const int tj0 = tjp * 2, tj1 = tjp * 2 + 1;
            f4v acc0[2][2], acc1[2][2];
            #pragma unroll
            for (int m = 0; m < 2; ++m)
                #pragma unroll
                for (int n = 0; n < 2; ++n) {
                    acc0[m][n] = (f4v){0.f, 0.f, 0.f, 0.f};
                    acc1[m][n] = (f4v){0.f, 0.f, 0.f, 0.f};
                }

            const __hip_bfloat16* Ab  = A  + (size_t)(i0 + ti * 128) * DP;
            const __hip_bfloat16* Bb0 = Bm + (size_t)(j0 + tj0 * 128) * DP;
            const __hip_bfloat16* Bb1 = Bm + (size_t)(j0 + tj1 * 128) * DP;

            KLOOP2

            // C/D layout: col = lane&15, row = (lane>>4)*4 + reg
            ROWCOL_EPI(acc0, tj0)
            ROWCOL_EPI(acc1, tj1)
        }
    }
    __syncthreads();
    // flush strip-maxes: tid<512 rows, tid>=512 cols (parallel)
    if (tid < 512) {
        const int r = tid;
        unsigned short t16[16];
        #pragma unroll
        for (int s = 0; s < 16; ++s) t16[s] = rowsm[s][r];
        uint4 o0, o1;
        o0.x = t16[0] | ((unsigned)t16[1] << 16);  o0.y = t16[2] | ((unsigned)t16[3] << 16);
        o0.z = t16[4] | ((unsigned)t16[5] << 16);  o0.w = t16[6] | ((unsigned)t16[7] << 16);
        o1.x = t16[8] | ((unsigned)t16[9] << 16);  o1.y = t16[10] | ((unsigned)t16[11] << 16);
        o1.z = t16[12] | ((unsigned)t16[13] << 16); o1.w = t16[14] | ((unsigned)t16[15] << 16);
        uint4* rdst = reinterpret_cast<uint4*>(rowsmax_g + (size_t)(i0 + r) * 512 + bx * 16);
        rdst[0] = o0; rdst[1] = o1;
    } else {
        const int r = tid - 512;
        uint4 q0 = *reinterpret_cast<uint4*>(&colsm[r][0]);
        uint4 q1 = *reinterpret_cast<uint4*>(&colsm[r][8]);
        uint4* cdst = reinterpret_cast<uint4*>(colsmax_g + (size_t)(j0 + r) * 512 + by * 16);
        cdst[0] = q0; cdst[1] = q1;
    }
}

// ---------------------------------------------------------------------------
// Kernel 3: per row/col, 10th-largest strip-max -> float lower-bound Tlb.
// ---------------------------------------------------------------------------
__global__ __launch_bounds__(256) void thresh_kernel(
        const unsigned short* __restrict__ rowsmax_g,
        const unsigned short* __restrict__ colsmax_g,
        float* __restrict__ Tlb_row, float* __restrict__ Tlb_col,
        unsigned* __restrict__ rowcnt, unsigned* __restrict__ colcnt) {
    const int t = blockIdx.x * 256 + threadIdx.x;
    const bool isRow = t < NN;
    const int idx = isRow ? t : t - NN;
    const unsigned short* src = (isRow ? rowsmax_g : colsmax_g) + (size_t)idx * 512;

    unsigned lst[10];
    #pragma unroll
    for (int q = 0; q < 10; ++q) lst[q] = 0u;

    const uint4* p = reinterpret_cast<const uint4*>(src);
    for (int c = 0; c < 64; ++c) {
        uint4 q = p[c];
        unsigned v0 = q.x & 0xFFFFu, v1 = q.x >> 16;
        unsigned v2 = q.y & 0xFFFFu, v3 = q.y >> 16;
        unsigned v4 = q.z & 0xFFFFu, v5 = q.z >> 16;
        unsigned v6 = q.w & 0xFFFFu, v7 = q.w >> 16;
        unsigned g01 = v0 > v1 ? v0 : v1, g23 = v2 > v3 ? v2 : v3;
        unsigned g45 = v4 > v5 ? v4 : v5, g67 = v6 > v7 ? v6 : v7;
        unsigned ga = g01 > g23 ? g01 : g23, gb = g45 > g67 ? g45 : g67;
        unsigned g = ga > gb ? ga : gb;
        if (g > lst[9]) {
            if (v0 > lst[9]) ins10(lst, v0);
            if (v1 > lst[9]) ins10(lst, v1);
            if (v2 > lst[9]) ins10(lst, v2);
            if (v3 > lst[9]) ins10(lst, v3);
            if (v4 > lst[9]) ins10(lst, v4);
            if (v5 > lst[9]) ins10(lst, v5);
            if (v6 > lst[9]) ins10(lst, v6);
            if (v7 > lst[9]) ins10(lst, v7);
        }
    }
    float f = key2f16(lst[9]);
    float lb = f - fabsf(f) * 0.002f - 1e-6f;   // f16 ulp safety margin
    if (isRow) { Tlb_row[idx] = lb; rowcnt[idx] = 0u; }
    else       { Tlb_col[idx] = lb; colcnt[idx] = 0u; }
}

// passB per-tile filter epilogue for one acc/tj
#define FILTER_EPI(ACC, TJ)                                                    \
    {                                                                          \
        const int c0i = (TJ) * 128 + wc * 32 + (lane & 15);                    \
        const int c1i = c0i + 16;                                              \
        const float tc0 = Tcol_s[c0i], tc1 = Tcol_s[c1i];                      \
        float vm = -1e30f;                                                     \
        _Pragma("unroll")                                                      \
        for (int m = 0; m < 2; ++m) {                                          \
            float a = fmaxf(fmaxf(ACC[m][0][0], ACC[m][0][1]),                 \
                            fmaxf(ACC[m][0][2], ACC[m][0][3]));                \
            float b = fmaxf(fmaxf(ACC[m][1][0], ACC[m][1][1]),                 \
                            fmaxf(ACC[m][1][2], ACC[m][1][3]));                \
            vm = fmaxf(vm, fmaxf(a, b));                                       \
        }                                                                      \
        if (vm >= fminf(trmin, fminf(tc0, tc1))) {                             \
            _Pragma("unroll")                                                  \
            for (int m = 0; m < 2; ++m) {                                      \
                _Pragma("unroll")                                              \
                for (int r = 0; r < 4; ++r) {                                  \
                    const int rl = ti * 128 + wr * 32 + m * 16 + ((lane >> 4) << 2) + r; \
                    const float T = Trow_s[rl];                                \
                    const float v0 = ACC[m][0][r], v1 = ACC[m][1][r];          \
                    if (v0 >= T) {                                             \
                        unsigned p = atomicAdd(&scnt[0], 1u);                  \
                        if (p < CAPL) sbuf[0][p] = make_uint2((unsigned)(i0 + rl), __float_as_uint(v0)); \
                        else { unsigned q = atomicAdd(&rowcnt[i0 + rl], 1u);   \
                               if (q < CAP) rowbuf[(size_t)(i0 + rl) * CAP + q] = v0; } \
                    }                                                          \
                    if (v1 >= T) {                                             \
                        unsigned p = atomicAdd(&scnt[0], 1u);                  \
                        if (p < CAPL) sbuf[0][p] = make_uint2((unsigned)(i0 + rl), __float_as_uint(v1)); \
                        else { unsigned q = atomicAdd(&rowcnt[i0 + rl], 1u);   \
                               if (q < CAP) rowbuf[(size_t)(i0 + rl) * CAP + q] = v1; } \
                    }                                                          \
                    if (v0 >= tc0) {                                           \
                        unsigned p = atomicAdd(&scnt[1], 1u);                  \
                        if (p < CAPL) sbuf[1][p] = make_uint2((unsigned)(j0 + c0i), __float_as_uint(v0)); \
                        else { unsigned q = atomicAdd(&colcnt[j0 + c0i], 1u);  \
                               if (q < CAP) colbuf[(size_t)(j0 + c0i) * CAP + q] = v0; } \
                    }                                                          \
                    if (v1 >= tc1) {                                           \
                        unsigned p = atomicAdd(&scnt[1], 1u);                  \
                        if (p < CAPL) sbuf[1][p] = make_uint2((unsigned)(j0 + c1i), __float_as_uint(v1)); \
                        else { unsigned q = atomicAdd(&colcnt[j0 + c1i], 1u);  \
                               if (q < CAP) colbuf[(size_t)(j0 + c1i) * CAP + q] = v1; } \
                    }                                                          \
                }                                                              \
            }                                                                  \
        }                                                                      \
    }

// ---------------------------------------------------------------------------
// Kernel 4 (pass B): GEMM + threshold filter; survivors via LDS stacks.
// tj-paired pipelined staging; LDS ~106 KB.
// ---------------------------------------------------------------------------
__global__ __launch_bounds__(1024) void passB_kernel(
        const __hip_bfloat16* __restrict__ A, const __hip_bfloat16* __restrict__ Bm,
        const float* __restrict__ Tlb_row, const float* __restrict__ Tlb_col,
        unsigned* __restrict__ rowcnt, unsigned* __restrict__ colcnt,
        float* __restrict__ rowbuf, float* __restrict__ colbuf) {
    __shared__ __align__(16) char u_lds[2 * BUFSZ];
    __shared__ float Trow_s[512];
    __shared__ float Tcol_s[512];
    __shared__ unsigned scnt[2];
    __shared__ uint2 sbuf[2][CAPL];

    const int tid = threadIdx.x;
    const int lane = tid & 63;
    const int w = tid >> 6;          // 0..15
    const int wr = w >> 2, wc = w & 3;
    int by, bx; xcd_map(blockIdx.x, by, bx);
    const int i0 = by * 512, j0 = bx * 512;

    if (tid < 512) Trow_s[tid] = Tlb_row[i0 + tid];
    else           Tcol_s[tid - 512] = Tlb_col[j0 + tid - 512];
    if (tid < 2) scnt[tid] = 0u;
    __syncthreads();

    for (int ti = 0; ti < 4; ++ti) {
        float trmin = 1e30f;
        #pragma unroll
        for (int m = 0; m < 2; ++m)
            #pragma unroll
            for (int r = 0; r < 4; ++r)
                trmin = fminf(trmin, Trow_s[ti * 128 + wr * 32 + m * 16 + ((lane >> 4) << 2) + r]);

        for (int tjp = 0; tjp < 2; ++tjp) {
            const int tj0 = tjp * 2, tj1 = tjp * 2 + 1;
            f4v acc0[2][2], acc1[2][2];
            #pragma unroll
            for (int m = 0; m < 2; ++m)
                #pragma unroll
                for (int n = 0; n < 2; ++n) {
                    acc0[m][n] = (f4v){0.f, 0.f, 0.f, 0.f};
                    acc1[m][n] = (f4v){0.f, 0.f, 0.f, 0.f};
                }

            const __hip_bfloat16* Ab  = A  + (size_t)(i0 + ti * 128) * DP;
            const __hip_bfloat16* Bb0 = Bm + (size_t)(j0 + tj0 * 128) * DP;
            const __hip_bfloat16* Bb1 = Bm + (size_t)(j0 + tj1 * 128) * DP;

            KLOOP2

            FILTER_EPI(acc0, tj0)
            FILTER_EPI(acc1, tj1)
        }
    }

    // parallel flush: independent global atomics, one latency round-trip
    __syncthreads();
    {
        const unsigned nr = scnt[0] < CAPL ? scnt[0] : CAPL;
        const unsigned nc = scnt[1] < CAPL ? scnt[1] : CAPL;
        for (unsigned i = tid; i < nr; i += 1024) {
            uint2 e = sbuf[0][i];
            unsigned p = atomicAdd(&rowcnt[e.x], 1u);
            if (p < CAP) rowbuf[(size_t)e.x * CAP + p] = __uint_as_float(e.y);
        }
        for (unsigned i = tid; i < nc; i += 1024) {
            uint2 e = sbuf[1][i];
            unsigned p = atomicAdd(&colcnt[e.x], 1u);
            if (p < CAP) colbuf[(size_t)e.x * CAP + p] = __uint_as_float(e.y);
        }
    }
}

// ---------------------------------------------------------------------------
// Kernel 5: exact top-10 of survivors -> rt / rs.
// ---------------------------------------------------------------------------
__global__ __launch_bounds__(256) void final_kernel(
        const unsigned* __restrict__ rowcnt, const unsigned* __restrict__ colcnt,
        const float* __restrict__ rowbuf, const float* __restrict__ colbuf,
        float* __restrict__ rt, float* __restrict__ rs) {
    const int t = blockIdx.x * 256 + threadIdx.x;
    const bool isRow = t < NN;
    const int idx = isRow ? t : t - NN;
    const unsigned cn = (isRow ? rowcnt : colcnt)[idx];
    const int n = (int)(cn < CAP ? cn : CAP);
    const float* buf = (isRow ? rowbuf : colbuf) + (size_t)idx * CAP;

    float lst[10];
    #pragma unroll
    for (int q = 0; q < 10; ++q) lst[q] = -1e30f;
    for (int i = 0; i < n; ++i) {
        float v = buf[i];
        if (v > lst[9]) ins10f(lst, v);
    }
    float s = 0.f;
    #pragma unroll
    for (int q = 0; q < 10; ++q) s += lst[q];
    s *= 0.1f;
    (isRow ? rt : rs)[idx] = s;
}

// ---------------------------------------------------------------------------
// Kernel 6: gathered dots + CSLS logits.
// ---------------------------------------------------------------------------
__global__ __launch_bounds__(256) void logits_kernel(
        const __hip_bfloat16* __restrict__ srcH, const __hip_bfloat16* __restrict__ tgtH,
        const int* __restrict__ sidx, const int* __restrict__ tidx,
        const float* __restrict__ rt, const float* __restrict__ rs,
        float* __restrict__ out) {
    const int b    = blockIdx.x;
    const int lane = threadIdx.x & 63;
    const int w    = threadIdx.x >> 6;

    const int s0 = sidx[b * KK];
    const int t0 = tidx[b * KK];
    float ps[5], pt[5];
    #pragma unroll
    for (int j = 0; j < 5; ++j) {
        int d = lane + 64 * j;
        ps[j] = __bfloat162float(srcH[(size_t)s0 * DP + d]);
        pt[j] = __bfloat162float(tgtH[(size_t)t0 * DP + d]);
    }
    const float rt_s0 = rt[s0];
    const float rs_t0 = rs[t0];

    for (int kk = w; kk < KK; kk += 4) {
        const int it = tidx[b * KK + kk];
        const int is = sidx[b * KK + kk];
        float a = 0.f, c = 0.f;
        #pragma unroll
        for (int j = 0; j < 5; ++j) {
            int d = lane + 64 * j;
            a += ps[j] * __bfloat162float(tgtH[(size_t)it * DP + d]);
            c += pt[j] * __bfloat162float(srcH[(size_t)is * DP + d]);
        }
        #pragma unroll
        for (int o = 32; o; o >>= 1) {
            a += __shfl_xor(a, o);
            c += __shfl_xor(c, o);
        }
        if (lane == 0) {
            out[b * KK + kk]           = 2.f * a - rt_s0 - rs[it];
            out[BB * KK + b * KK + kk] = 2.f * c - rs_t0 - rt[is];
        }
    }
}

// ---------------------------------------------------------------------------
extern "C" void kernel_launch(void* const* d_in, const int* in_sizes, int n_in,
                              void* d_out, int out_size, void* d_ws, size_t ws_size,
                              hipStream_t stream) {
    const float* nf_src = (const float*)d_in[0];
    const float* nf_tgt = (const float*)d_in[1];
    const int*   sidx   = (const int*)d_in[2];
    const int*   tidx   = (const int*)d_in[3];
    const float* svs    = (const float*)d_in[4];
    const float* tvs    = (const float*)d_in[5];

    char* ws = (char*)d_ws;
    const size_t SZ_H  = (size_t)NN * DP * 2;         // bf16 feats
    const size_t SZ_SM = (size_t)NN * 512 * 2;        // strip-maxes
    __hip_bfloat16* srcH = (__hip_bfloat16*)ws;
    __hip_bfloat16* tgtH = (__hip_bfloat16*)(ws + SZ_H);
    unsigned short* rowsmax = (unsigned short*)(ws + 2 * SZ_H);
    unsigned short* colsmax = (unsigned short*)(ws + 2 * SZ_H + SZ_SM);
    // rowbuf/colbuf alias the rowsmax region (consumed by thresh before passB)
    float* rowbuf = (float*)(ws + 2 * SZ_H);
    float* colbuf = (float*)(ws + 2 * SZ_H + (size_t)NN * CAP * 4);
    char* tail = ws + 2 * SZ_H + 2 * SZ_SM;
    float* Tlb_row = (float*)(tail);
    float* Tlb_col = (float*)(tail + 65536);
    unsigned* rowcnt = (unsigned*)(tail + 2 * 65536);
    unsigned* colcnt = (unsigned*)(tail + 3 * 65536);
    float* rt = (float*)(tail + 4 * 65536);
    float* rs = (float*)(tail + 5 * 65536);

    tower_kernel<<<NN / 4, 256, 0, stream>>>(nf_src, svs, srcH);
    tower_kernel<<<NN / 4, 256, 0, stream>>>(nf_tgt, tvs, tgtH);
    passA_kernel<<<1024, 1024, 0, stream>>>(srcH, tgtH, rowsmax, colsmax);
    thresh_kernel<<<(2 * NN) / 256, 256, 0, stream>>>(rowsmax, colsmax, Tlb_row, Tlb_col,
                                                      rowcnt, colcnt);
    passB_kernel<<<1024, 1024, 0, stream>>>(srcH, tgtH, Tlb_row, Tlb_col,
                                            rowcnt, colcnt, rowbuf, colbuf);
    final_kernel<<<(2 * NN) / 256, 256, 0, stream>>>(rowcnt, colcnt, rowbuf, colbuf, rt, rs);
    logits_kernel<<<BB, 256, 0, stream>>>(srcH, tgtH, sidx, tidx, rt, rs, (float*)d_out);
}